// Round 1
// baseline (672.706 us; speedup 1.0000x reference)
//
#include <hip/hip_runtime.h>
#include <cstdint>
#include <cstddef>

#define GN 16384              // pixels per image (128*128)
#define QK_SCALE 0.17677669529663687f   // 32^-0.5

__device__ __forceinline__ float qk_act(float z) {
  // elu(z) + 1
  return z > 0.0f ? z + 1.0f : expf(z);
}

// ---------------------------------------------------------------------------
// GEMM: Out[b][o][n] = sum_c Wm[o][c] * X[b][c][n]
// X planar [B][SK][GN] (we read channels 0..255 of each batch's SK-channel block)
// Tile: 64 outs x 128 pixels, BK=32, 256 threads, 4x8 microtile.
// KACT: apply elu(v*scale)+1 to output channels [256,512) (the k channels).
// ---------------------------------------------------------------------------
template<int M, bool KACT, int SK>
__global__ __launch_bounds__(256) void gemm_planar(
    const float* __restrict__ Wm, const float* __restrict__ X,
    float* __restrict__ Out)
{
  __shared__ __align__(16) float Ws[32][68];    // [c][o], padded
  __shared__ __align__(16) float Xs[32][128];   // [c][pix]
  const int tid = threadIdx.x;
  const int b  = blockIdx.z;
  const int o0 = blockIdx.y * 64;
  const int n0 = blockIdx.x * 128;
  const int tx = tid & 15;   // pixel group (8 px)
  const int ty = tid >> 4;   // out group (4 o)

  float acc[4][8];
#pragma unroll
  for (int i = 0; i < 4; ++i)
#pragma unroll
    for (int j = 0; j < 8; ++j) acc[i][j] = 0.0f;

  const float* Xb = X + (size_t)b * SK * GN;

  for (int kt = 0; kt < 256; kt += 32) {
#pragma unroll
    for (int t = 0; t < 4; ++t) {
      int idx = t * 256 + tid;
      int ch = idx >> 5;
      int c4 = idx & 31;
      *(float4*)&Xs[ch][c4 * 4] =
          *(const float4*)(Xb + (size_t)(kt + ch) * GN + n0 + c4 * 4);
    }
#pragma unroll
    for (int t = 0; t < 2; ++t) {
      int idx = t * 256 + tid;
      int r = idx >> 3;
      int q = idx & 7;
      float4 w = *(const float4*)(Wm + (size_t)(o0 + r) * 256 + kt + q * 4);
      Ws[q * 4 + 0][r] = w.x;
      Ws[q * 4 + 1][r] = w.y;
      Ws[q * 4 + 2][r] = w.z;
      Ws[q * 4 + 3][r] = w.w;
    }
    __syncthreads();
#pragma unroll
    for (int kk = 0; kk < 32; ++kk) {
      float4 wv = *(const float4*)&Ws[kk][ty * 4];
      float4 xa = *(const float4*)&Xs[kk][tx * 8];
      float4 xb = *(const float4*)&Xs[kk][tx * 8 + 4];
      float wr[4] = {wv.x, wv.y, wv.z, wv.w};
      float xr[8] = {xa.x, xa.y, xa.z, xa.w, xb.x, xb.y, xb.z, xb.w};
#pragma unroll
      for (int i = 0; i < 4; ++i)
#pragma unroll
        for (int j = 0; j < 8; ++j) acc[i][j] += wr[i] * xr[j];
    }
    __syncthreads();
  }

#pragma unroll
  for (int i = 0; i < 4; ++i) {
    int o = o0 + ty * 4 + i;
    float vals[8];
#pragma unroll
    for (int j = 0; j < 8; ++j) vals[j] = acc[i][j];
    if (KACT && o >= 256 && o < 512) {
#pragma unroll
      for (int j = 0; j < 8; ++j) vals[j] = qk_act(vals[j] * QK_SCALE);
    }
    float* op = Out + ((size_t)b * M + o) * GN + n0 + tx * 8;
    float4 r0 = {vals[0], vals[1], vals[2], vals[3]};
    float4 r1 = {vals[4], vals[5], vals[6], vals[7]};
    *(float4*)op = r0;
    *(float4*)(op + 4) = r1;
  }
}

// ---------------------------------------------------------------------------
// kv[bh][d][e] = sum_n k'[bh][d][n] * v[bh][e][n];  ksum[bh][d] = sum_n k'.
// Grid: (16 chunks of 1024 px, 32 bh). Partial sums via atomics (zeroed before).
// ---------------------------------------------------------------------------
__global__ __launch_bounds__(256) void kv_ksum(
    const float* __restrict__ qkv, float* __restrict__ kvbuf,
    float* __restrict__ ksumbuf)
{
  __shared__ __align__(16) float ksh[32][68];
  __shared__ __align__(16) float vsh[32][68];
  const int tid = threadIdx.x;
  const int bh = blockIdx.y;
  const int b = bh >> 3;
  const int head = bh & 7;
  const int dd = tid & 31;   // k channel
  const int eg = tid >> 5;   // v channel group (4 e's)

  const float* Kb = qkv + ((size_t)b * 768 + 256 + head * 32) * GN;
  const float* Vb = qkv + ((size_t)b * 768 + 512 + head * 32) * GN;
  const int pbase = blockIdx.x * 1024;

  float acc[4] = {0.f, 0.f, 0.f, 0.f};
  float ksacc = 0.f;

  for (int st = 0; st < 1024; st += 64) {
    const int p0 = pbase + st;
#pragma unroll
    for (int t = 0; t < 2; ++t) {
      int idx = t * 256 + tid;
      int ch = idx >> 4;
      int c4 = idx & 15;
      *(float4*)&ksh[ch][c4 * 4] = *(const float4*)(Kb + (size_t)ch * GN + p0 + c4 * 4);
      *(float4*)&vsh[ch][c4 * 4] = *(const float4*)(Vb + (size_t)ch * GN + p0 + c4 * 4);
    }
    __syncthreads();
#pragma unroll
    for (int pg = 0; pg < 16; ++pg) {
      float4 kd = *(const float4*)&ksh[dd][pg * 4];
#pragma unroll
      for (int j = 0; j < 4; ++j) {
        float4 vv = *(const float4*)&vsh[eg * 4 + j][pg * 4];
        acc[j] += kd.x * vv.x + kd.y * vv.y + kd.z * vv.z + kd.w * vv.w;
      }
      if (eg == 0) ksacc += kd.x + kd.y + kd.z + kd.w;
    }
    __syncthreads();
  }

  float* kvp = kvbuf + ((size_t)bh * 32 + dd) * 32 + eg * 4;
#pragma unroll
  for (int j = 0; j < 4; ++j) atomicAdd(kvp + j, acc[j]);
  if (eg == 0) atomicAdd(ksumbuf + bh * 32 + dd, ksacc);
}

// ---------------------------------------------------------------------------
// Pool raw q: 2x2 means -> qp2 [B][256][64*64], 4x4 means -> qp4 [B][256][32*32]
// One thread per 4x4 block.
// ---------------------------------------------------------------------------
__global__ __launch_bounds__(256) void pool_q(
    const float* __restrict__ qkv, float* __restrict__ qp2,
    float* __restrict__ qp4)
{
  const int g = blockIdx.x * 256 + threadIdx.x;   // < 4*256*32*32
  const int x4 = g & 31;
  const int y4 = (g >> 5) & 31;
  const int bc = g >> 10;     // b*256 + c
  const int b = bc >> 8;
  const int c = bc & 255;
  const float* src = qkv + ((size_t)b * 768 + c) * GN + (y4 * 4) * 128 + x4 * 4;
  float4 r0 = *(const float4*)(src);
  float4 r1 = *(const float4*)(src + 128);
  float4 r2 = *(const float4*)(src + 256);
  float4 r3 = *(const float4*)(src + 384);
  float m00 = (r0.x + r0.y + r1.x + r1.y) * 0.25f;
  float m01 = (r0.z + r0.w + r1.z + r1.w) * 0.25f;
  float m10 = (r2.x + r2.y + r3.x + r3.y) * 0.25f;
  float m11 = (r2.z + r2.w + r3.z + r3.w) * 0.25f;
  float m4 = (m00 + m01 + m10 + m11) * 0.25f;
  float* p2 = qp2 + (size_t)bc * 4096 + (y4 * 2) * 64 + x4 * 2;
  float2 wa = {m00, m01};
  float2 wb = {m10, m11};
  *(float2*)p2 = wa;
  *(float2*)(p2 + 64) = wb;
  qp4[(size_t)bc * 1024 + y4 * 32 + x4] = m4;
}

// ---------------------------------------------------------------------------
// Pooled attention: ao[b][ch][p] = (act(qp*scale) @ kv) / max(act(qp)·ksum, eps)
// One thread per pooled pixel. Np in {4096, 1024}.
// ---------------------------------------------------------------------------
__global__ __launch_bounds__(256) void pooled_attn(
    const float* __restrict__ qp, const float* __restrict__ kvbuf,
    const float* __restrict__ ksumbuf, float* __restrict__ ao, int Np)
{
  __shared__ __align__(16) float kv_s[32][32];
  __shared__ float ks_s[32];
  const int tid = threadIdx.x;
  const int bh = blockIdx.y;
  const int b = bh >> 3;
  const int head = bh & 7;
  const int p = blockIdx.x * 256 + tid;

  const float* kvb = kvbuf + (size_t)bh * 1024;
#pragma unroll
  for (int t = 0; t < 4; ++t) ((float*)kv_s)[t * 256 + tid] = kvb[t * 256 + tid];
  if (tid < 32) ks_s[tid] = ksumbuf[bh * 32 + tid];
  __syncthreads();

  const float* q0 = qp + ((size_t)(b * 256 + head * 32)) * Np + p;
  float qa[32];
#pragma unroll
  for (int dd = 0; dd < 32; ++dd) qa[dd] = qk_act(q0[(size_t)dd * Np] * QK_SCALE);

  float o1[32];
#pragma unroll
  for (int e = 0; e < 32; ++e) o1[e] = 0.f;
  float norm = 0.f;
#pragma unroll
  for (int dd = 0; dd < 32; ++dd) {
    float qv = qa[dd];
    norm += qv * ks_s[dd];
#pragma unroll
    for (int e4 = 0; e4 < 8; ++e4) {
      float4 kvv = *(const float4*)&kv_s[dd][e4 * 4];
      o1[e4 * 4 + 0] += qv * kvv.x;
      o1[e4 * 4 + 1] += qv * kvv.y;
      o1[e4 * 4 + 2] += qv * kvv.z;
      o1[e4 * 4 + 3] += qv * kvv.w;
    }
  }
  norm = fmaxf(norm, 1e-6f);
  float inv1 = 1.0f / norm;
  float* a0 = ao + ((size_t)(b * 256 + head * 32)) * Np + p;
#pragma unroll
  for (int e = 0; e < 32; ++e) a0[(size_t)e * Np] = o1[e] * inv1;
}

// ---------------------------------------------------------------------------
// Fused final: per pixel, scale-1 attention + bilinear-upsampled pooled outputs,
// softmax-weighted sum -> pre (written into the dead v region of qkv).
// ---------------------------------------------------------------------------
__global__ __launch_bounds__(256) void fused_out(
    const float* __restrict__ qkv, const float* __restrict__ kvbuf,
    const float* __restrict__ ksumbuf, const float* __restrict__ ao2,
    const float* __restrict__ ao4, const float* __restrict__ swin,
    float* __restrict__ prebase)
{
  __shared__ __align__(16) float kv_s[32][32];
  __shared__ float ks_s[32];
  const int tid = threadIdx.x;
  const int bh = blockIdx.y;
  const int b = bh >> 3;
  const int head = bh & 7;
  const int n = blockIdx.x * 256 + tid;

  const float* kvb = kvbuf + (size_t)bh * 1024;
#pragma unroll
  for (int t = 0; t < 4; ++t) ((float*)kv_s)[t * 256 + tid] = kvb[t * 256 + tid];
  if (tid < 32) ks_s[tid] = ksumbuf[bh * 32 + tid];
  __syncthreads();

  // softmax over the 3 scale weights
  float s0 = swin[0], s1 = swin[1], s2 = swin[2];
  float mx = fmaxf(s0, fmaxf(s1, s2));
  float ex0 = expf(s0 - mx), ex1 = expf(s1 - mx), ex2 = expf(s2 - mx);
  float sinv = 1.0f / (ex0 + ex1 + ex2);
  float sw0 = ex0 * sinv, sw1 = ex1 * sinv, sw2 = ex2 * sinv;

  const float* q0 = qkv + ((size_t)b * 768 + head * 32) * GN + n;
  float qa[32];
#pragma unroll
  for (int dd = 0; dd < 32; ++dd) qa[dd] = qk_act(q0[(size_t)dd * GN] * QK_SCALE);

  float o1[32];
#pragma unroll
  for (int e = 0; e < 32; ++e) o1[e] = 0.f;
  float norm = 0.f;
#pragma unroll
  for (int dd = 0; dd < 32; ++dd) {
    float qv = qa[dd];
    norm += qv * ks_s[dd];
#pragma unroll
    for (int e4 = 0; e4 < 8; ++e4) {
      float4 kvv = *(const float4*)&kv_s[dd][e4 * 4];
      o1[e4 * 4 + 0] += qv * kvv.x;
      o1[e4 * 4 + 1] += qv * kvv.y;
      o1[e4 * 4 + 2] += qv * kvv.z;
      o1[e4 * 4 + 3] += qv * kvv.w;
    }
  }
  norm = fmaxf(norm, 1e-6f);
  float inv1 = 1.0f / norm;

  const int y = n >> 7, x = n & 127;
  // scale 2 (pooled 64x64), half-pixel mapping
  float fy2 = 0.5f * (float)y - 0.25f;
  float fx2 = 0.5f * (float)x - 0.25f;
  int y20 = (int)floorf(fy2); float wy2 = fy2 - (float)y20;
  int x20 = (int)floorf(fx2); float wx2 = fx2 - (float)x20;
  int y20c = y20 > 0 ? y20 : 0; int y21c = (y20 + 1) < 63 ? (y20 + 1) : 63;
  int x20c = x20 > 0 ? x20 : 0; int x21c = (x20 + 1) < 63 ? (x20 + 1) : 63;
  // scale 4 (pooled 32x32)
  float fy4 = 0.25f * (float)y - 0.375f;
  float fx4 = 0.25f * (float)x - 0.375f;
  int y40 = (int)floorf(fy4); float wy4 = fy4 - (float)y40;
  int x40 = (int)floorf(fx4); float wx4 = fx4 - (float)x40;
  int y40c = y40 > 0 ? y40 : 0; int y41c = (y40 + 1) < 31 ? (y40 + 1) : 31;
  int x40c = x40 > 0 ? x40 : 0; int x41c = (x40 + 1) < 31 ? (x40 + 1) : 31;

  const float* a2 = ao2 + ((size_t)(b * 256 + head * 32)) * 4096;
  const float* a4 = ao4 + ((size_t)(b * 256 + head * 32)) * 1024;
  float* pr = prebase + ((size_t)b * 768 + 512 + head * 32) * GN + n;

#pragma unroll
  for (int e = 0; e < 32; ++e) {
    const float* c2 = a2 + (size_t)e * 4096;
    float u2 = (1.f - wy2) * ((1.f - wx2) * c2[y20c * 64 + x20c] + wx2 * c2[y20c * 64 + x21c])
             +         wy2 * ((1.f - wx2) * c2[y21c * 64 + x20c] + wx2 * c2[y21c * 64 + x21c]);
    const float* c4 = a4 + (size_t)e * 1024;
    float u4 = (1.f - wy4) * ((1.f - wx4) * c4[y40c * 32 + x40c] + wx4 * c4[y40c * 32 + x41c])
             +         wy4 * ((1.f - wx4) * c4[y41c * 32 + x40c] + wx4 * c4[y41c * 32 + x41c]);
    pr[(size_t)e * GN] = sw0 * o1[e] * inv1 + sw1 * u2 + sw2 * u4;
  }
}

// ---------------------------------------------------------------------------
extern "C" void kernel_launch(void* const* d_in, const int* in_sizes, int n_in,
                              void* d_out, int out_size, void* d_ws, size_t ws_size,
                              hipStream_t stream) {
  const float* x     = (const float*)d_in[0];
  const float* Wqkv  = (const float*)d_in[1];
  const float* Wproj = (const float*)d_in[2];
  const float* swin  = (const float*)d_in[3];
  float* out = (float*)d_out;
  float* ws  = (float*)d_ws;

  // workspace layout (floats)
  float* qkv = ws;                                        // 4*768*16384
  float* kvbuf   = ws + (size_t)4 * 768 * GN;             // 32*1024
  float* ksumbuf = kvbuf + 32768;                         // 1024
  float* qp2 = ksumbuf + 1024;                            // 4*256*4096
  float* ao2 = qp2 + (size_t)4 * 256 * 4096;              // 4*256*4096
  float* qp4 = ao2 + (size_t)4 * 256 * 4096;              // 4*256*1024
  float* ao4 = qp4 + (size_t)4 * 256 * 1024;              // 4*256*1024
  // total ~243.4 MB

  hipMemsetAsync(kvbuf, 0, (32768 + 1024) * sizeof(float), stream);

  dim3 blk(256);
  // 1. qkv = Wqkv @ x  (k channels activated in epilogue; q,v raw)
  gemm_planar<768, true, 256><<<dim3(128, 12, 4), blk, 0, stream>>>(Wqkv, x, qkv);
  // 2. kv + ksum reduction
  kv_ksum<<<dim3(16, 32), blk, 0, stream>>>(qkv, kvbuf, ksumbuf);
  // 3. pool raw q
  pool_q<<<dim3(4096), blk, 0, stream>>>(qkv, qp2, qp4);
  // 4/5. pooled attention
  pooled_attn<<<dim3(16, 32), blk, 0, stream>>>(qp2, kvbuf, ksumbuf, ao2, 4096);
  pooled_attn<<<dim3(4, 32), blk, 0, stream>>>(qp4, kvbuf, ksumbuf, ao4, 1024);
  // 6. fused scale-1 + upsample + weighted sum -> pre (overlaid on v region)
  fused_out<<<dim3(64, 32), blk, 0, stream>>>(qkv, kvbuf, ksumbuf, ao2, ao4, swin, qkv);
  // 7. projection
  gemm_planar<256, false, 768><<<dim3(128, 4, 4), blk, 0, stream>>>(Wproj, qkv + (size_t)512 * GN, out);
}

// Round 4
// 501.767 us; speedup vs baseline: 1.3407x; 1.3407x over previous
//
#include <hip/hip_runtime.h>
#include <cstdint>
#include <cstddef>

#define GN 16384              // pixels per image (128*128)
#define QK_SCALE 0.17677669529663687f   // 32^-0.5

typedef __attribute__((ext_vector_type(8))) __bf16 bf16x8;
typedef __attribute__((ext_vector_type(4))) float f32x4;
typedef __attribute__((ext_vector_type(8))) unsigned short us8;
typedef __attribute__((ext_vector_type(4))) unsigned short us4;

__device__ __forceinline__ float qk_act(float z) {
  return z > 0.0f ? z + 1.0f : expf(z);   // elu(z)+1
}

__device__ __forceinline__ unsigned short f2bf_rn(float v) {
  union { float f; unsigned u; } a; a.f = v;
  unsigned u = a.u;
  unsigned r = u + 0x7fffu + ((u >> 16) & 1u);
  return (unsigned short)(r >> 16);
}
__device__ __forceinline__ float bf2f(unsigned short h) {
  union { unsigned u; float f; } a; a.u = ((unsigned)h) << 16; return a.f;
}

#define GLLDS(SRC, DST) __builtin_amdgcn_global_load_lds( \
    (const __attribute__((address_space(1))) void*)(SRC), \
    (__attribute__((address_space(3))) void*)(DST), 16, 0, 0)

// ---------------------------------------------------------------------------
// Split a weight matrix (row-major [m][k]) into bf16 hi/lo.
// ---------------------------------------------------------------------------
__global__ __launch_bounds__(256) void split_w(
    const float* __restrict__ in, unsigned short* __restrict__ h,
    unsigned short* __restrict__ l, int n4)
{
  int i = blockIdx.x * 256 + threadIdx.x;
  if (i >= n4) return;
  float4 v = ((const float4*)in)[i];
  us4 vh, vl;
  vh[0] = f2bf_rn(v.x); vl[0] = f2bf_rn(v.x - bf2f(vh[0]));
  vh[1] = f2bf_rn(v.y); vl[1] = f2bf_rn(v.y - bf2f(vh[1]));
  vh[2] = f2bf_rn(v.z); vl[2] = f2bf_rn(v.z - bf2f(vh[2]));
  vh[3] = f2bf_rn(v.w); vl[3] = f2bf_rn(v.w - bf2f(vh[3]));
  ((us4*)h)[i] = vh;
  ((us4*)l)[i] = vl;
}

// ---------------------------------------------------------------------------
// Transpose + split ONE batch of x: [256][GN] f32 -> xh/xl [GN][256] bf16.
// Tile 32 channels x 64 pixels via LDS.
// ---------------------------------------------------------------------------
__global__ __launch_bounds__(256) void split_x_t(
    const float* __restrict__ xb, unsigned short* __restrict__ xh,
    unsigned short* __restrict__ xl)
{
  __shared__ float ts[32][65];
  const int t  = threadIdx.x;
  const int n0 = blockIdx.x * 64;
  const int c0 = blockIdx.y * 32;
  {
    const int c  = t >> 3;
    const int nc = (t & 7) * 8;
    const float* src = xb + ((size_t)(c0 + c)) * GN + n0 + nc;
    float4 v0 = *(const float4*)src;
    float4 v1 = *(const float4*)(src + 4);
    ts[c][nc + 0] = v0.x; ts[c][nc + 1] = v0.y; ts[c][nc + 2] = v0.z; ts[c][nc + 3] = v0.w;
    ts[c][nc + 4] = v1.x; ts[c][nc + 5] = v1.y; ts[c][nc + 6] = v1.z; ts[c][nc + 7] = v1.w;
  }
  __syncthreads();
  {
    const int n  = t & 63;
    const int cg = (t >> 6) * 8;
    us8 vh, vl;
#pragma unroll
    for (int j = 0; j < 8; ++j) {
      float v = ts[cg + j][n];
      unsigned short hh = f2bf_rn(v);
      vh[j] = hh;
      vl[j] = f2bf_rn(v - bf2f(hh));
    }
    size_t off = ((size_t)(n0 + n)) * 256 + c0 + cg;
    *(us8*)(xh + off) = vh;
    *(us8*)(xl + off) = vl;
  }
}

// ---------------------------------------------------------------------------
// Split-bf16 MFMA GEMM:  Out[b][m][n] = sum_k W[m][k] * X[b][n][k]
// W: [M][256] bf16 hi/lo row-major.  X: [GN][256] bf16 hi/lo per batch,
// batch stride XBS (ushorts).  Out: planar f32 [b][M][GN].
// 128x128 tile, BK=32, 4 waves, 16x16x32 MFMA, m97 structure.
// KACT: apply elu(v*scale)+1 to rows [256,512).
// ---------------------------------------------------------------------------
template<int M, bool KACT>
__global__ __launch_bounds__(256) void gemm_mfma(
    const unsigned short* __restrict__ Wh, const unsigned short* __restrict__ Wl,
    const unsigned short* __restrict__ Xh, const unsigned short* __restrict__ Xl,
    float* __restrict__ Out, size_t XBS)
{
  constexpr int MT = M / 128;
  __shared__ __align__(16) char lds[32768];   // Ah | Al | Bh | Bl (8KB each)
  const int tid = threadIdx.x;
  const int w = tid >> 6;
  const int l = tid & 63;

  // XCD chunk swizzle (grid divisible by 8)
  const int per  = gridDim.x >> 3;
  const int bid  = blockIdx.x;
  const int lbid = (bid & 7) * per + (bid >> 3);
  const int mt = lbid % MT;                 // fastest: M-tiles share the X slab
  const int nt = (lbid / MT) & 127;
  const int b  = lbid / (MT * 128);

  const int m0 = mt * 128;
  const int n0 = nt * 128;

  const unsigned short* xh_b = Xh + (size_t)b * XBS;
  const unsigned short* xl_b = Xl + (size_t)b * XBS;

  f32x4 acc[4][4];
  const f32x4 zz = {0.f, 0.f, 0.f, 0.f};
#pragma unroll
  for (int i = 0; i < 4; ++i)
#pragma unroll
    for (int j = 0; j < 4; ++j) acc[i][j] = zz;

  const int wm = w >> 1, wn = w & 1;
  const int lr = l & 15, lk = l >> 4;
  const int ra  = wm * 64 + lr;
  const int rb  = wn * 64 + lr;
  const int cxa = (lk ^ (lr & 3)) << 4;     // swizzled 16B-chunk byte offset

  for (int kt = 0; kt < 256; kt += 32) {
    // ---- stage 32KB via global_load_lds (16B/lane, XOR-swizzled source) ----
#pragma unroll
    for (int j = 0; j < 2; ++j) {
      const int r0 = w * 32 + j * 16;       // wave-uniform
      const int r  = r0 + (l >> 2);
      const int lc = (((l & 3) ^ (r & 3)) << 3);   // logical elem offset in row
      const size_t wrow = (size_t)(m0 + r) * 256 + kt + lc;
      const size_t xrow = (size_t)(n0 + r) * 256 + kt + lc;
      GLLDS(Wh + wrow,   lds + 0     + r0 * 64);
      GLLDS(Wl + wrow,   lds + 8192  + r0 * 64);
      GLLDS(xh_b + xrow, lds + 16384 + r0 * 64);
      GLLDS(xl_b + xrow, lds + 24576 + r0 * 64);
    }
    __syncthreads();

    // ---- fragments (ds_read_b128, contiguous k-map, inverse swizzle) ----
    bf16x8 ah[4], al[4], bh[4], bl[4];
#pragma unroll
    for (int s = 0; s < 4; ++s) {
      const int oa = (ra + s * 16) * 64 + cxa;
      const int ob = (rb + s * 16) * 64 + cxa;
      ah[s] = *(const bf16x8*)(lds + 0     + oa);
      al[s] = *(const bf16x8*)(lds + 8192  + oa);
      bh[s] = *(const bf16x8*)(lds + 16384 + ob);
      bl[s] = *(const bf16x8*)(lds + 24576 + ob);
    }
    // ---- 3-term split MFMA: hh + hl + lh ----
#pragma unroll
    for (int ms = 0; ms < 4; ++ms)
#pragma unroll
      for (int ns = 0; ns < 4; ++ns) {
        acc[ms][ns] = __builtin_amdgcn_mfma_f32_16x16x32_bf16(ah[ms], bh[ns], acc[ms][ns], 0, 0, 0);
        acc[ms][ns] = __builtin_amdgcn_mfma_f32_16x16x32_bf16(ah[ms], bl[ns], acc[ms][ns], 0, 0, 0);
        acc[ms][ns] = __builtin_amdgcn_mfma_f32_16x16x32_bf16(al[ms], bh[ns], acc[ms][ns], 0, 0, 0);
      }
    __syncthreads();
  }

  // ---- epilogue: C/D map col=lane&15, row=(lane>>4)*4+reg ----
  const bool act = KACT && (m0 >= 256 && m0 < 512);
#pragma unroll
  for (int ms = 0; ms < 4; ++ms)
#pragma unroll
    for (int ns = 0; ns < 4; ++ns) {
      const int m = m0 + wm * 64 + ms * 16 + lk * 4;
      const int n = n0 + wn * 64 + ns * 16 + lr;
      float* op = Out + ((size_t)b * M + m) * GN + n;
#pragma unroll
      for (int r = 0; r < 4; ++r) {
        float v = acc[ms][ns][r];
        if (act) v = qk_act(v * QK_SCALE);
        op[(size_t)r * GN] = v;
      }
    }
}

// ---------------------------------------------------------------------------
// kv[bh][d][e] = sum_n k'[bh][d][n] * v[bh][e][n];  ksum[bh][d] = sum_n k'.
// ---------------------------------------------------------------------------
__global__ __launch_bounds__(256) void kv_ksum(
    const float* __restrict__ qkv, float* __restrict__ kvbuf,
    float* __restrict__ ksumbuf)
{
  __shared__ __align__(16) float ksh[32][68];
  __shared__ __align__(16) float vsh[32][68];
  const int tid = threadIdx.x;
  const int bh = blockIdx.y;
  const int b = bh >> 3;
  const int head = bh & 7;
  const int dd = tid & 31;
  const int eg = tid >> 5;

  const float* Kb = qkv + ((size_t)b * 768 + 256 + head * 32) * GN;
  const float* Vb = qkv + ((size_t)b * 768 + 512 + head * 32) * GN;
  const int pbase = blockIdx.x * 1024;

  float acc[4] = {0.f, 0.f, 0.f, 0.f};
  float ksacc = 0.f;

  for (int st = 0; st < 1024; st += 64) {
    const int p0 = pbase + st;
#pragma unroll
    for (int t = 0; t < 2; ++t) {
      int idx = t * 256 + tid;
      int ch = idx >> 4;
      int c4 = idx & 15;
      *(float4*)&ksh[ch][c4 * 4] = *(const float4*)(Kb + (size_t)ch * GN + p0 + c4 * 4);
      *(float4*)&vsh[ch][c4 * 4] = *(const float4*)(Vb + (size_t)ch * GN + p0 + c4 * 4);
    }
    __syncthreads();
#pragma unroll
    for (int pg = 0; pg < 16; ++pg) {
      float4 kd = *(const float4*)&ksh[dd][pg * 4];
#pragma unroll
      for (int j = 0; j < 4; ++j) {
        float4 vv = *(const float4*)&vsh[eg * 4 + j][pg * 4];
        acc[j] += kd.x * vv.x + kd.y * vv.y + kd.z * vv.z + kd.w * vv.w;
      }
      if (eg == 0) ksacc += kd.x + kd.y + kd.z + kd.w;
    }
    __syncthreads();
  }

  float* kvp = kvbuf + ((size_t)bh * 32 + dd) * 32 + eg * 4;
#pragma unroll
  for (int j = 0; j < 4; ++j) atomicAdd(kvp + j, acc[j]);
  if (eg == 0) atomicAdd(ksumbuf + bh * 32 + dd, ksacc);
}

// ---------------------------------------------------------------------------
// Pool raw q: 2x2 -> qp2 [B][256][4096], 4x4 -> qp4 [B][256][1024]
// ---------------------------------------------------------------------------
__global__ __launch_bounds__(256) void pool_q(
    const float* __restrict__ qkv, float* __restrict__ qp2,
    float* __restrict__ qp4)
{
  const int g = blockIdx.x * 256 + threadIdx.x;
  const int x4 = g & 31;
  const int y4 = (g >> 5) & 31;
  const int bc = g >> 10;
  const int b = bc >> 8;
  const int c = bc & 255;
  const float* src = qkv + ((size_t)b * 768 + c) * GN + (y4 * 4) * 128 + x4 * 4;
  float4 r0 = *(const float4*)(src);
  float4 r1 = *(const float4*)(src + 128);
  float4 r2 = *(const float4*)(src + 256);
  float4 r3 = *(const float4*)(src + 384);
  float m00 = (r0.x + r0.y + r1.x + r1.y) * 0.25f;
  float m01 = (r0.z + r0.w + r1.z + r1.w) * 0.25f;
  float m10 = (r2.x + r2.y + r3.x + r3.y) * 0.25f;
  float m11 = (r2.z + r2.w + r3.z + r3.w) * 0.25f;
  float m4 = (m00 + m01 + m10 + m11) * 0.25f;
  float* p2 = qp2 + (size_t)bc * 4096 + (y4 * 2) * 64 + x4 * 2;
  float2 wa = {m00, m01};
  float2 wb = {m10, m11};
  *(float2*)p2 = wa;
  *(float2*)(p2 + 64) = wb;
  qp4[(size_t)bc * 1024 + y4 * 32 + x4] = m4;
}

// ---------------------------------------------------------------------------
// Pooled attention IN-PLACE: qp[p] <- (act(qp*scale) @ kv) / max(..., eps).
// Each thread reads exactly the elements it overwrites; no cross-thread reuse.
// ---------------------------------------------------------------------------
__global__ __launch_bounds__(256) void pooled_attn(
    float* qp, const float* __restrict__ kvbuf,
    const float* __restrict__ ksumbuf, int Np)
{
  __shared__ __align__(16) float kv_s[32][32];
  __shared__ float ks_s[32];
  const int tid = threadIdx.x;
  const int bh = blockIdx.y;
  const int b = bh >> 3;
  const int head = bh & 7;
  const int p = blockIdx.x * 256 + tid;

  const float* kvb = kvbuf + (size_t)bh * 1024;
#pragma unroll
  for (int t = 0; t < 4; ++t) ((float*)kv_s)[t * 256 + tid] = kvb[t * 256 + tid];
  if (tid < 32) ks_s[tid] = ksumbuf[bh * 32 + tid];
  __syncthreads();

  float* q0 = qp + ((size_t)(b * 256 + head * 32)) * Np + p;
  float qa[32];
#pragma unroll
  for (int dd = 0; dd < 32; ++dd) qa[dd] = qk_act(q0[(size_t)dd * Np] * QK_SCALE);

  float o1[32];
#pragma unroll
  for (int e = 0; e < 32; ++e) o1[e] = 0.f;
  float norm = 0.f;
#pragma unroll
  for (int dd = 0; dd < 32; ++dd) {
    float qv = qa[dd];
    norm += qv * ks_s[dd];
#pragma unroll
    for (int e4 = 0; e4 < 8; ++e4) {
      float4 kvv = *(const float4*)&kv_s[dd][e4 * 4];
      o1[e4 * 4 + 0] += qv * kvv.x;
      o1[e4 * 4 + 1] += qv * kvv.y;
      o1[e4 * 4 + 2] += qv * kvv.z;
      o1[e4 * 4 + 3] += qv * kvv.w;
    }
  }
  norm = fmaxf(norm, 1e-6f);
  float inv1 = 1.0f / norm;
#pragma unroll
  for (int e = 0; e < 32; ++e) q0[(size_t)e * Np] = o1[e] * inv1;
}

// ---------------------------------------------------------------------------
// Fused final: scale-1 attention + bilinear upsample of pooled outputs,
// softmax-weighted; emits proj input as PIXEL-MAJOR bf16 hi/lo [b][n][256].
// ---------------------------------------------------------------------------
__global__ __launch_bounds__(256) void fused_out(
    const float* __restrict__ qkv, const float* __restrict__ kvbuf,
    const float* __restrict__ ksumbuf, const float* __restrict__ ao2,
    const float* __restrict__ ao4, const float* __restrict__ swin,
    unsigned short* __restrict__ preh, unsigned short* __restrict__ prel,
    size_t PBS)
{
  __shared__ __align__(16) float kv_s[32][32];
  __shared__ float ks_s[32];
  const int tid = threadIdx.x;
  const int bh = blockIdx.y;
  const int b = bh >> 3;
  const int head = bh & 7;
  const int n = blockIdx.x * 256 + tid;

  const float* kvb = kvbuf + (size_t)bh * 1024;
#pragma unroll
  for (int t = 0; t < 4; ++t) ((float*)kv_s)[t * 256 + tid] = kvb[t * 256 + tid];
  if (tid < 32) ks_s[tid] = ksumbuf[bh * 32 + tid];
  __syncthreads();

  float s0 = swin[0], s1 = swin[1], s2 = swin[2];
  float mx = fmaxf(s0, fmaxf(s1, s2));
  float ex0 = expf(s0 - mx), ex1 = expf(s1 - mx), ex2 = expf(s2 - mx);
  float sinv = 1.0f / (ex0 + ex1 + ex2);
  float sw0 = ex0 * sinv, sw1 = ex1 * sinv, sw2 = ex2 * sinv;

  const float* q0 = qkv + ((size_t)b * 768 + head * 32) * GN + n;
  float qa[32];
#pragma unroll
  for (int dd = 0; dd < 32; ++dd) qa[dd] = qk_act(q0[(size_t)dd * GN] * QK_SCALE);

  float o1[32];
#pragma unroll
  for (int e = 0; e < 32; ++e) o1[e] = 0.f;
  float norm = 0.f;
#pragma unroll
  for (int dd = 0; dd < 32; ++dd) {
    float qv = qa[dd];
    norm += qv * ks_s[dd];
#pragma unroll
    for (int e4 = 0; e4 < 8; ++e4) {
      float4 kvv = *(const float4*)&kv_s[dd][e4 * 4];
      o1[e4 * 4 + 0] += qv * kvv.x;
      o1[e4 * 4 + 1] += qv * kvv.y;
      o1[e4 * 4 + 2] += qv * kvv.z;
      o1[e4 * 4 + 3] += qv * kvv.w;
    }
  }
  norm = fmaxf(norm, 1e-6f);
  float inv1 = 1.0f / norm;

  const int y = n >> 7, x = n & 127;
  float fy2 = 0.5f * (float)y - 0.25f;
  float fx2 = 0.5f * (float)x - 0.25f;
  int y20 = (int)floorf(fy2); float wy2 = fy2 - (float)y20;
  int x20 = (int)floorf(fx2); float wx2 = fx2 - (float)x20;
  int y20c = y20 > 0 ? y20 : 0; int y21c = (y20 + 1) < 63 ? (y20 + 1) : 63;
  int x20c = x20 > 0 ? x20 : 0; int x21c = (x20 + 1) < 63 ? (x20 + 1) : 63;
  float fy4 = 0.25f * (float)y - 0.375f;
  float fx4 = 0.25f * (float)x - 0.375f;
  int y40 = (int)floorf(fy4); float wy4 = fy4 - (float)y40;
  int x40 = (int)floorf(fx4); float wx4 = fx4 - (float)x40;
  int y40c = y40 > 0 ? y40 : 0; int y41c = (y40 + 1) < 31 ? (y40 + 1) : 31;
  int x40c = x40 > 0 ? x40 : 0; int x41c = (x40 + 1) < 31 ? (x40 + 1) : 31;

  const float* a2 = ao2 + ((size_t)(b * 256 + head * 32)) * 4096;
  const float* a4 = ao4 + ((size_t)(b * 256 + head * 32)) * 1024;
  unsigned short* ph = preh + (size_t)b * PBS + (size_t)n * 256 + head * 32;
  unsigned short* pl = prel + (size_t)b * PBS + (size_t)n * 256 + head * 32;

#pragma unroll
  for (int t4 = 0; t4 < 4; ++t4) {
    us8 vh, vl;
#pragma unroll
    for (int j2 = 0; j2 < 8; ++j2) {
      const int e = t4 * 8 + j2;
      const float* c2 = a2 + (size_t)e * 4096;
      float u2 = (1.f - wy2) * ((1.f - wx2) * c2[y20c * 64 + x20c] + wx2 * c2[y20c * 64 + x21c])
               +         wy2 * ((1.f - wx2) * c2[y21c * 64 + x20c] + wx2 * c2[y21c * 64 + x21c]);
      const float* c4 = a4 + (size_t)e * 1024;
      float u4 = (1.f - wy4) * ((1.f - wx4) * c4[y40c * 32 + x40c] + wx4 * c4[y40c * 32 + x41c])
               +         wy4 * ((1.f - wx4) * c4[y41c * 32 + x40c] + wx4 * c4[y41c * 32 + x41c]);
      float val = sw0 * o1[e] * inv1 + sw1 * u2 + sw2 * u4;
      unsigned short hh = f2bf_rn(val);
      vh[j2] = hh;
      vl[j2] = f2bf_rn(val - bf2f(hh));
    }
    *(us8*)(ph + t4 * 8) = vh;
    *(us8*)(pl + t4 * 8) = vl;
  }
}

// ---------------------------------------------------------------------------
extern "C" void kernel_launch(void* const* d_in, const int* in_sizes, int n_in,
                              void* d_out, int out_size, void* d_ws, size_t ws_size,
                              hipStream_t stream) {
  const float* x     = (const float*)d_in[0];
  const float* Wqkv  = (const float*)d_in[1];
  const float* Wproj = (const float*)d_in[2];
  const float* swin  = (const float*)d_in[3];
  float* out = (float*)d_out;
  float* ws  = (float*)d_ws;

  // ---- workspace layout (floats); total 55,870,464 f = 223.5 MB ----
  float* qkv = ws;                                   // 50,331,648 f
  float* pool = ws + (size_t)50331648;               // 5,242,880 f region
  // xt (per-batch transposed split x) overlays pools; dead before pools written
  unsigned short* xt_h = (unsigned short*)pool;      // 4,194,304 us
  unsigned short* xt_l = xt_h + (size_t)4194304;     // 4,194,304 us
  float* qp2 = pool;                                 // 4,194,304 f (in-place ao2)
  float* qp4 = pool + (size_t)4194304;               // 1,048,576 f (in-place ao4)
  float* kvb  = pool + (size_t)5242880;              // 32,768 f
  float* ksum = kvb + 32768;                         // 1,024 f
  unsigned short* wh1 = (unsigned short*)(ksum + 1024);  // 196,608 us
  unsigned short* wl1 = wh1 + 196608;                // 196,608 us
  unsigned short* wh2 = wl1 + 196608;                // 65,536 us
  unsigned short* wl2 = wh2 + 65536;                 // 65,536 us
  // pre (proj input) overlaid on dead v region of qkv, pixel-major bf16 hi/lo
  unsigned short* preh = (unsigned short*)qkv + (size_t)1024 * GN;
  unsigned short* prel = (unsigned short*)qkv + (size_t)1280 * GN;
  const size_t PBS = (size_t)1536 * GN;              // per-batch stride (ushorts)

  hipMemsetAsync(kvb, 0, (32768 + 1024) * sizeof(float), stream);

  dim3 blk(256);
  // 0. weight splits
  split_w<<<dim3(192), blk, 0, stream>>>(Wqkv, wh1, wl1, 49152);
  split_w<<<dim3(64),  blk, 0, stream>>>(Wproj, wh2, wl2, 16384);
  // 1+2. per batch: transpose+split x slab, then qkv GEMM for that batch
  for (int b = 0; b < 4; ++b) {
    split_x_t<<<dim3(256, 8), blk, 0, stream>>>(x + (size_t)b * 256 * GN, xt_h, xt_l);
    gemm_mfma<768, true><<<dim3(768), blk, 0, stream>>>(
        wh1, wl1, xt_h, xt_l, qkv + (size_t)b * 768 * GN, 0);
  }
  // 3. kv + ksum reduction
  kv_ksum<<<dim3(16, 32), blk, 0, stream>>>(qkv, kvb, ksum);
  // 4. pool raw q (xt dead now; pools overlay it)
  pool_q<<<dim3(4096), blk, 0, stream>>>(qkv, qp2, qp4);
  // 5. pooled attention, in place
  pooled_attn<<<dim3(16, 32), blk, 0, stream>>>(qp2, kvb, ksum, 4096);
  pooled_attn<<<dim3(4, 32), blk, 0, stream>>>(qp4, kvb, ksum, 1024);
  // 6. fused scale-1 + upsample + weighted sum -> pre (bf16 hi/lo, pixel-major)
  fused_out<<<dim3(64, 32), blk, 0, stream>>>(qkv, kvb, ksum, qp2, qp4, swin,
                                              preh, prel, PBS);
  // 7. projection via split-bf16 MFMA (4 batches, stride PBS)
  gemm_mfma<256, false><<<dim3(1024), blk, 0, stream>>>(wh2, wl2, preh, prel, out, PBS);
}

// Round 5
// 468.561 us; speedup vs baseline: 1.4357x; 1.0709x over previous
//
#include <hip/hip_runtime.h>
#include <cstdint>
#include <cstddef>

#define GN 16384              // pixels per image (128*128)
#define QK_SCALE 0.17677669529663687f   // 32^-0.5

typedef __attribute__((ext_vector_type(8))) __bf16 bf16x8;
typedef __attribute__((ext_vector_type(4))) float f32x4;
typedef __attribute__((ext_vector_type(8))) unsigned short us8;
typedef __attribute__((ext_vector_type(4))) unsigned short us4;

__device__ __forceinline__ float qk_act(float z) {
  return z > 0.0f ? z + 1.0f : __expf(z);   // elu(z)+1
}

__device__ __forceinline__ unsigned short f2bf_rn(float v) {
  union { float f; unsigned u; } a; a.f = v;
  unsigned u = a.u;
  unsigned r = u + 0x7fffu + ((u >> 16) & 1u);
  return (unsigned short)(r >> 16);
}
__device__ __forceinline__ float bf2f(unsigned short h) {
  union { unsigned u; float f; } a; a.u = ((unsigned)h) << 16; return a.f;
}

#define GLLDS(SRC, DST) __builtin_amdgcn_global_load_lds( \
    (const __attribute__((address_space(1))) void*)(SRC), \
    (__attribute__((address_space(3))) void*)(DST), 16, 0, 0)

// ---------------------------------------------------------------------------
// Split a weight matrix (row-major [m][k]) into bf16 hi/lo.
// ---------------------------------------------------------------------------
__global__ __launch_bounds__(256) void split_w(
    const float* __restrict__ in, unsigned short* __restrict__ h,
    unsigned short* __restrict__ l, int n4)
{
  int i = blockIdx.x * 256 + threadIdx.x;
  if (i >= n4) return;
  float4 v = ((const float4*)in)[i];
  us4 vh, vl;
  vh[0] = f2bf_rn(v.x); vl[0] = f2bf_rn(v.x - bf2f(vh[0]));
  vh[1] = f2bf_rn(v.y); vl[1] = f2bf_rn(v.y - bf2f(vh[1]));
  vh[2] = f2bf_rn(v.z); vl[2] = f2bf_rn(v.z - bf2f(vh[2]));
  vh[3] = f2bf_rn(v.w); vl[3] = f2bf_rn(v.w - bf2f(vh[3]));
  ((us4*)h)[i] = vh;
  ((us4*)l)[i] = vl;
}

// ---------------------------------------------------------------------------
// Transpose + split ONE batch of x: [256][GN] f32 -> xh/xl [GN][256] bf16.
// ---------------------------------------------------------------------------
__global__ __launch_bounds__(256) void split_x_t(
    const float* __restrict__ xb, unsigned short* __restrict__ xh,
    unsigned short* __restrict__ xl)
{
  __shared__ float ts[32][65];
  const int t  = threadIdx.x;
  const int n0 = blockIdx.x * 64;
  const int c0 = blockIdx.y * 32;
  {
    const int c  = t >> 3;
    const int nc = (t & 7) * 8;
    const float* src = xb + ((size_t)(c0 + c)) * GN + n0 + nc;
    float4 v0 = *(const float4*)src;
    float4 v1 = *(const float4*)(src + 4);
    ts[c][nc + 0] = v0.x; ts[c][nc + 1] = v0.y; ts[c][nc + 2] = v0.z; ts[c][nc + 3] = v0.w;
    ts[c][nc + 4] = v1.x; ts[c][nc + 5] = v1.y; ts[c][nc + 6] = v1.z; ts[c][nc + 7] = v1.w;
  }
  __syncthreads();
  {
    const int n  = t & 63;
    const int cg = (t >> 6) * 8;
    us8 vh, vl;
#pragma unroll
    for (int j = 0; j < 8; ++j) {
      float v = ts[cg + j][n];
      unsigned short hh = f2bf_rn(v);
      vh[j] = hh;
      vl[j] = f2bf_rn(v - bf2f(hh));
    }
    size_t off = ((size_t)(n0 + n)) * 256 + c0 + cg;
    *(us8*)(xh + off) = vh;
    *(us8*)(xl + off) = vl;
  }
}

// ---------------------------------------------------------------------------
// Split-bf16 MFMA GEMM:  Out[b][m][n] = sum_k W[m][k] * X[b][n][k]
// HEADMAJ=false: X rows are [n][256] contiguous.
// HEADMAJ=true : X is [head][GN][32] per batch (head = k>>5) — the fused_out
//                output layout. 16B staging chunks never cross a head.
// 128x128 tile, BK=32, 4 waves, 16x16x32 MFMA, m97 structure.
// KACT: apply elu(v*scale)+1 to rows [256,512).
// ---------------------------------------------------------------------------
template<int M, bool KACT, bool HEADMAJ>
__global__ __launch_bounds__(256) void gemm_mfma(
    const unsigned short* __restrict__ Wh, const unsigned short* __restrict__ Wl,
    const unsigned short* __restrict__ Xh, const unsigned short* __restrict__ Xl,
    float* __restrict__ Out, size_t XBS)
{
  constexpr int MT = M / 128;
  __shared__ __align__(16) char lds[32768];   // Ah | Al | Bh | Bl (8KB each)
  const int tid = threadIdx.x;
  const int w = tid >> 6;
  const int l = tid & 63;

  // XCD chunk swizzle (grid divisible by 8)
  const int per  = gridDim.x >> 3;
  const int bid  = blockIdx.x;
  const int lbid = (bid & 7) * per + (bid >> 3);
  const int mt = lbid % MT;                 // fastest: M-tiles share the X slab
  const int nt = (lbid / MT) & 127;
  const int b  = lbid / (MT * 128);

  const int m0 = mt * 128;
  const int n0 = nt * 128;

  const unsigned short* xh_b = Xh + (size_t)b * XBS;
  const unsigned short* xl_b = Xl + (size_t)b * XBS;

  f32x4 acc[4][4];
  const f32x4 zz = {0.f, 0.f, 0.f, 0.f};
#pragma unroll
  for (int i = 0; i < 4; ++i)
#pragma unroll
    for (int j = 0; j < 4; ++j) acc[i][j] = zz;

  const int wm = w >> 1, wn = w & 1;
  const int lr = l & 15, lk = l >> 4;
  const int ra  = wm * 64 + lr;
  const int rb  = wn * 64 + lr;
  const int cxa = (lk ^ (lr & 3)) << 4;     // swizzled 16B-chunk byte offset

  for (int kt = 0; kt < 256; kt += 32) {
    // ---- stage 32KB via global_load_lds (16B/lane, XOR-swizzled source) ----
#pragma unroll
    for (int j = 0; j < 2; ++j) {
      const int r0 = w * 32 + j * 16;       // wave-uniform
      const int r  = r0 + (l >> 2);
      const int lc = (((l & 3) ^ (r & 3)) << 3);   // logical elem offset in row
      const size_t wrow = (size_t)(m0 + r) * 256 + kt + lc;
      const size_t xrow = HEADMAJ
          ? (size_t)(kt >> 5) * ((size_t)GN * 32) + (size_t)(n0 + r) * 32 + lc
          : (size_t)(n0 + r) * 256 + kt + lc;
      GLLDS(Wh + wrow,   lds + 0     + r0 * 64);
      GLLDS(Wl + wrow,   lds + 8192  + r0 * 64);
      GLLDS(xh_b + xrow, lds + 16384 + r0 * 64);
      GLLDS(xl_b + xrow, lds + 24576 + r0 * 64);
    }
    __syncthreads();

    // ---- fragments (ds_read_b128, contiguous k-map, inverse swizzle) ----
    bf16x8 ah[4], al[4], bh[4], bl[4];
#pragma unroll
    for (int s = 0; s < 4; ++s) {
      const int oa = (ra + s * 16) * 64 + cxa;
      const int ob = (rb + s * 16) * 64 + cxa;
      ah[s] = *(const bf16x8*)(lds + 0     + oa);
      al[s] = *(const bf16x8*)(lds + 8192  + oa);
      bh[s] = *(const bf16x8*)(lds + 16384 + ob);
      bl[s] = *(const bf16x8*)(lds + 24576 + ob);
    }
    // ---- 3-term split MFMA: hh + hl + lh ----
#pragma unroll
    for (int ms = 0; ms < 4; ++ms)
#pragma unroll
      for (int ns = 0; ns < 4; ++ns) {
        acc[ms][ns] = __builtin_amdgcn_mfma_f32_16x16x32_bf16(ah[ms], bh[ns], acc[ms][ns], 0, 0, 0);
        acc[ms][ns] = __builtin_amdgcn_mfma_f32_16x16x32_bf16(ah[ms], bl[ns], acc[ms][ns], 0, 0, 0);
        acc[ms][ns] = __builtin_amdgcn_mfma_f32_16x16x32_bf16(al[ms], bh[ns], acc[ms][ns], 0, 0, 0);
      }
    __syncthreads();
  }

  // ---- epilogue: C/D map col=lane&15, row=(lane>>4)*4+reg ----
  const bool act = KACT && (m0 >= 256 && m0 < 512);
#pragma unroll
  for (int ms = 0; ms < 4; ++ms)
#pragma unroll
    for (int ns = 0; ns < 4; ++ns) {
      const int m = m0 + wm * 64 + ms * 16 + lk * 4;
      const int n = n0 + wn * 64 + ns * 16 + lr;
      float* op = Out + ((size_t)b * M + m) * GN + n;
#pragma unroll
      for (int r = 0; r < 4; ++r) {
        float v = acc[ms][ns][r];
        if (act) v = qk_act(v * QK_SCALE);
        op[(size_t)r * GN] = v;
      }
    }
}

// ---------------------------------------------------------------------------
// kv[bh][d][e] = sum_n k'[bh][d][n] * v[bh][e][n];  ksum[bh][d] = sum_n k'.
// ---------------------------------------------------------------------------
__global__ __launch_bounds__(256) void kv_ksum(
    const float* __restrict__ qkv, float* __restrict__ kvbuf,
    float* __restrict__ ksumbuf)
{
  __shared__ __align__(16) float ksh[32][68];
  __shared__ __align__(16) float vsh[32][68];
  const int tid = threadIdx.x;
  const int bh = blockIdx.y;
  const int b = bh >> 3;
  const int head = bh & 7;
  const int dd = tid & 31;
  const int eg = tid >> 5;

  const float* Kb = qkv + ((size_t)b * 768 + 256 + head * 32) * GN;
  const float* Vb = qkv + ((size_t)b * 768 + 512 + head * 32) * GN;
  const int pbase = blockIdx.x * 1024;

  float acc[4] = {0.f, 0.f, 0.f, 0.f};
  float ksacc = 0.f;

  for (int st = 0; st < 1024; st += 64) {
    const int p0 = pbase + st;
#pragma unroll
    for (int t = 0; t < 2; ++t) {
      int idx = t * 256 + tid;
      int ch = idx >> 4;
      int c4 = idx & 15;
      *(float4*)&ksh[ch][c4 * 4] = *(const float4*)(Kb + (size_t)ch * GN + p0 + c4 * 4);
      *(float4*)&vsh[ch][c4 * 4] = *(const float4*)(Vb + (size_t)ch * GN + p0 + c4 * 4);
    }
    __syncthreads();
#pragma unroll
    for (int pg = 0; pg < 16; ++pg) {
      float4 kd = *(const float4*)&ksh[dd][pg * 4];
#pragma unroll
      for (int j = 0; j < 4; ++j) {
        float4 vv = *(const float4*)&vsh[eg * 4 + j][pg * 4];
        acc[j] += kd.x * vv.x + kd.y * vv.y + kd.z * vv.z + kd.w * vv.w;
      }
      if (eg == 0) ksacc += kd.x + kd.y + kd.z + kd.w;
    }
    __syncthreads();
  }

  float* kvp = kvbuf + ((size_t)bh * 32 + dd) * 32 + eg * 4;
#pragma unroll
  for (int j = 0; j < 4; ++j) atomicAdd(kvp + j, acc[j]);
  if (eg == 0) atomicAdd(ksumbuf + bh * 32 + dd, ksacc);
}

// ---------------------------------------------------------------------------
// Pool raw q: 2x2 -> qp2 [B][256][4096], 4x4 -> qp4 [B][256][1024]
// ---------------------------------------------------------------------------
__global__ __launch_bounds__(256) void pool_q(
    const float* __restrict__ qkv, float* __restrict__ qp2,
    float* __restrict__ qp4)
{
  const int g = blockIdx.x * 256 + threadIdx.x;
  const int x4 = g & 31;
  const int y4 = (g >> 5) & 31;
  const int bc = g >> 10;
  const int b = bc >> 8;
  const int c = bc & 255;
  const float* src = qkv + ((size_t)b * 768 + c) * GN + (y4 * 4) * 128 + x4 * 4;
  float4 r0 = *(const float4*)(src);
  float4 r1 = *(const float4*)(src + 128);
  float4 r2 = *(const float4*)(src + 256);
  float4 r3 = *(const float4*)(src + 384);
  float m00 = (r0.x + r0.y + r1.x + r1.y) * 0.25f;
  float m01 = (r0.z + r0.w + r1.z + r1.w) * 0.25f;
  float m10 = (r2.x + r2.y + r3.x + r3.y) * 0.25f;
  float m11 = (r2.z + r2.w + r3.z + r3.w) * 0.25f;
  float m4 = (m00 + m01 + m10 + m11) * 0.25f;
  float* p2 = qp2 + (size_t)bc * 4096 + (y4 * 2) * 64 + x4 * 2;
  float2 wa = {m00, m01};
  float2 wb = {m10, m11};
  *(float2*)p2 = wa;
  *(float2*)(p2 + 64) = wb;
  qp4[(size_t)bc * 1024 + y4 * 32 + x4] = m4;
}

// ---------------------------------------------------------------------------
// Pooled attention IN-PLACE: qp[p] <- (act(qp*scale) @ kv) / max(..., eps).
// ---------------------------------------------------------------------------
__global__ __launch_bounds__(256) void pooled_attn(
    float* qp, const float* __restrict__ kvbuf,
    const float* __restrict__ ksumbuf, int Np)
{
  __shared__ __align__(16) float kv_s[32][32];
  __shared__ float ks_s[32];
  const int tid = threadIdx.x;
  const int bh = blockIdx.y;
  const int b = bh >> 3;
  const int head = bh & 7;
  const int p = blockIdx.x * 256 + tid;

  const float* kvb = kvbuf + (size_t)bh * 1024;
#pragma unroll
  for (int t = 0; t < 4; ++t) ((float*)kv_s)[t * 256 + tid] = kvb[t * 256 + tid];
  if (tid < 32) ks_s[tid] = ksumbuf[bh * 32 + tid];
  __syncthreads();

  float* q0 = qp + ((size_t)(b * 256 + head * 32)) * Np + p;
  float qa[32];
#pragma unroll
  for (int dd = 0; dd < 32; ++dd) qa[dd] = qk_act(q0[(size_t)dd * Np] * QK_SCALE);

  float o1[32];
#pragma unroll
  for (int e = 0; e < 32; ++e) o1[e] = 0.f;
  float norm = 0.f;
#pragma unroll
  for (int dd = 0; dd < 32; ++dd) {
    float qv = qa[dd];
    norm += qv * ks_s[dd];
#pragma unroll
    for (int e4 = 0; e4 < 8; ++e4) {
      float4 kvv = *(const float4*)&kv_s[dd][e4 * 4];
      o1[e4 * 4 + 0] += qv * kvv.x;
      o1[e4 * 4 + 1] += qv * kvv.y;
      o1[e4 * 4 + 2] += qv * kvv.z;
      o1[e4 * 4 + 3] += qv * kvv.w;
    }
  }
  norm = fmaxf(norm, 1e-6f);
  float inv1 = 1.0f / norm;
#pragma unroll
  for (int e = 0; e < 32; ++e) q0[(size_t)e * Np] = o1[e] * inv1;
}

// ---------------------------------------------------------------------------
// Fused final: scale-1 attention + bilinear upsample of pooled outputs
// (staged in LDS), softmax-weighted; emits proj input HEAD-MAJOR
// [b][head][n][32] bf16 hi/lo -> fully coalesced 64B/thread writes.
// Block: one (row-pair m, bh): 256 px, 2 image rows {2m, 2m+1}.
// ---------------------------------------------------------------------------
__global__ __launch_bounds__(256) void fused_out(
    const float* __restrict__ qkv, const float* __restrict__ kvbuf,
    const float* __restrict__ ksumbuf, const float* __restrict__ ao2,
    const float* __restrict__ ao4, const float* __restrict__ swin,
    unsigned short* __restrict__ preh, unsigned short* __restrict__ prel,
    size_t PBS)
{
  __shared__ __align__(16) float kv_s[32][32];     //  4 KB
  __shared__ float ks_s[32];
  __shared__ __align__(16) float a2_s[3][32][64];  // 24 KB: [row][e][x]
  __shared__ __align__(16) float a4_s[3][32][32];  // 12 KB
  const int tid = threadIdx.x;
  const int m  = blockIdx.x;            // row-pair index, y in {2m, 2m+1}
  const int bh = blockIdx.y;
  const int b = bh >> 3;
  const int head = bh & 7;
  const int n = m * 256 + tid;

  const float* kvb = kvbuf + (size_t)bh * 1024;
#pragma unroll
  for (int t = 0; t < 4; ++t) ((float*)kv_s)[t * 256 + tid] = kvb[t * 256 + tid];
  if (tid < 32) ks_s[tid] = ksumbuf[bh * 32 + tid];

  const float* a2 = ao2 + ((size_t)(b * 256 + head * 32)) * 4096;
  const float* a4 = ao4 + ((size_t)(b * 256 + head * 32)) * 1024;
  const int p = m >> 1;
  int r2[3], r4[3];
#pragma unroll
  for (int j = 0; j < 3; ++j) {
    int a = m - 1 + j; r2[j] = a < 0 ? 0 : (a > 63 ? 63 : a);
    int c = p - 1 + j; r4[j] = c < 0 ? 0 : (c > 31 ? 31 : c);
  }
  // stage ao2 rows {m-1,m,m+1}: 1536 float4, coalesced
#pragma unroll
  for (int t = 0; t < 6; ++t) {
    int fidx = t * 256 + tid;
    int x4 = fidx & 15, e = (fidx >> 4) & 31, j = fidx >> 9;
    *(float4*)&a2_s[j][e][x4 * 4] =
        *(const float4*)(a2 + (size_t)e * 4096 + r2[j] * 64 + x4 * 4);
  }
  // stage ao4 rows {p-1,p,p+1}: 768 float4
#pragma unroll
  for (int t = 0; t < 3; ++t) {
    int fidx = t * 256 + tid;
    int x4 = fidx & 7, e = (fidx >> 3) & 31, j = fidx >> 8;
    *(float4*)&a4_s[j][e][x4 * 4] =
        *(const float4*)(a4 + (size_t)e * 1024 + r4[j] * 32 + x4 * 4);
  }
  __syncthreads();

  float s0 = swin[0], s1 = swin[1], s2 = swin[2];
  float mx = fmaxf(s0, fmaxf(s1, s2));
  float ex0 = __expf(s0 - mx), ex1 = __expf(s1 - mx), ex2 = __expf(s2 - mx);
  float sinv = 1.0f / (ex0 + ex1 + ex2);
  float sw0 = ex0 * sinv, sw1 = ex1 * sinv, sw2 = ex2 * sinv;

  // ---- scale-1 linear attention for this pixel ----
  const float* q0 = qkv + ((size_t)b * 768 + head * 32) * GN + n;
  float qa[32];
#pragma unroll
  for (int dd = 0; dd < 32; ++dd) qa[dd] = qk_act(q0[(size_t)dd * GN] * QK_SCALE);

  float o1[32];
#pragma unroll
  for (int e = 0; e < 32; ++e) o1[e] = 0.f;
  float norm = 0.f;
#pragma unroll
  for (int dd = 0; dd < 32; ++dd) {
    float qv = qa[dd];
    norm += qv * ks_s[dd];
#pragma unroll
    for (int e4 = 0; e4 < 8; ++e4) {
      float4 kvv = *(const float4*)&kv_s[dd][e4 * 4];
      o1[e4 * 4 + 0] += qv * kvv.x;
      o1[e4 * 4 + 1] += qv * kvv.y;
      o1[e4 * 4 + 2] += qv * kvv.z;
      o1[e4 * 4 + 3] += qv * kvv.w;
    }
  }
  norm = fmaxf(norm, 1e-6f);
  float inv1 = 1.0f / norm;

  // ---- bilinear params (closed form; half-pixel mapping) ----
  const int yb = tid >> 7;                  // 0/1 -> y = 2m + yb
  const int x  = n & 127;
  // scale 2: y20 = m-1+yb (row j2=yb), wy2 = yb?0.25:0.75
  const int j2 = yb;
  const float wy2 = yb ? 0.25f : 0.75f;
  const int xu = x >> 1;
  const int x20 = xu - 1 + (x & 1);
  const float wx2 = (x & 1) ? 0.25f : 0.75f;
  const int x20c = x20 < 0 ? 0 : x20;
  const int x21c = (x20 + 1) < 63 ? (x20 + 1) : 63;
  // scale 4: y40 row j4 = m&1; wy4 per derivation
  const int j4 = m & 1;
  const float wy4 = (0.625f - 0.5f * (float)(m & 1)) + 0.25f * (float)yb;
  const int xq = x >> 2, xr = x & 3;
  const int x40 = xq - 1 + (xr >> 1);
  const float wx4 = ((xr & 1) ? 0.875f : 0.625f) - ((xr >> 1) ? 0.5f : 0.0f);
  const int x40c = x40 < 0 ? 0 : x40;
  const int x41c = (x40 + 1) < 31 ? (x40 + 1) : 31;

  const float wy2i = 1.f - wy2, wx2i = 1.f - wx2;
  const float wy4i = 1.f - wy4, wx4i = 1.f - wx4;

  // ---- combine + write head-major [head][n][32] (64B contig per thread) ----
  unsigned short* ph = preh + (size_t)b * PBS + (size_t)head * (GN * 32) + (size_t)n * 32;
  unsigned short* pl = prel + (size_t)b * PBS + (size_t)head * (GN * 32) + (size_t)n * 32;

#pragma unroll
  for (int t4 = 0; t4 < 4; ++t4) {
    us8 vh, vl;
#pragma unroll
    for (int j = 0; j < 8; ++j) {
      const int e = t4 * 8 + j;
      float u2 = wy2i * (wx2i * a2_s[j2][e][x20c] + wx2 * a2_s[j2][e][x21c])
               + wy2  * (wx2i * a2_s[j2 + 1][e][x20c] + wx2 * a2_s[j2 + 1][e][x21c]);
      float u4 = wy4i * (wx4i * a4_s[j4][e][x40c] + wx4 * a4_s[j4][e][x41c])
               + wy4  * (wx4i * a4_s[j4 + 1][e][x40c] + wx4 * a4_s[j4 + 1][e][x41c]);
      float val = sw0 * o1[e] * inv1 + sw1 * u2 + sw2 * u4;
      unsigned short hh = f2bf_rn(val);
      vh[j] = hh;
      vl[j] = f2bf_rn(val - bf2f(hh));
    }
    *(us8*)(ph + t4 * 8) = vh;
    *(us8*)(pl + t4 * 8) = vl;
  }
}

// ---------------------------------------------------------------------------
extern "C" void kernel_launch(void* const* d_in, const int* in_sizes, int n_in,
                              void* d_out, int out_size, void* d_ws, size_t ws_size,
                              hipStream_t stream) {
  const float* x     = (const float*)d_in[0];
  const float* Wqkv  = (const float*)d_in[1];
  const float* Wproj = (const float*)d_in[2];
  const float* swin  = (const float*)d_in[3];
  float* out = (float*)d_out;
  float* ws  = (float*)d_ws;

  // ---- workspace layout (floats); total 55,870,464 f = 223.5 MB ----
  float* qkv = ws;                                   // 50,331,648 f
  float* pool = ws + (size_t)50331648;               // 5,242,880 f region
  // xt (per-batch transposed split x) overlays pools; dead before pools written
  unsigned short* xt_h = (unsigned short*)pool;      // 4,194,304 us
  unsigned short* xt_l = xt_h + (size_t)4194304;     // 4,194,304 us
  float* qp2 = pool;                                 // 4,194,304 f (in-place ao2)
  float* qp4 = pool + (size_t)4194304;               // 1,048,576 f (in-place ao4)
  float* kvb  = pool + (size_t)5242880;              // 32,768 f
  float* ksum = kvb + 32768;                         // 1,024 f
  unsigned short* wh1 = (unsigned short*)(ksum + 1024);  // 196,608 us
  unsigned short* wl1 = wh1 + 196608;                // 196,608 us
  unsigned short* wh2 = wl1 + 196608;                // 65,536 us
  unsigned short* wl2 = wh2 + 65536;                 // 65,536 us
  // pre (proj input) overlaid on dead v region of qkv; head-major bf16 hi/lo
  unsigned short* preh = (unsigned short*)qkv + (size_t)1024 * GN;
  unsigned short* prel = (unsigned short*)qkv + (size_t)1280 * GN;
  const size_t PBS = (size_t)1536 * GN;              // per-batch stride (ushorts)

  hipMemsetAsync(kvb, 0, (32768 + 1024) * sizeof(float), stream);

  dim3 blk(256);
  // 0. weight splits
  split_w<<<dim3(192), blk, 0, stream>>>(Wqkv, wh1, wl1, 49152);
  split_w<<<dim3(64),  blk, 0, stream>>>(Wproj, wh2, wl2, 16384);
  // 1+2. per batch: transpose+split x slab, then qkv GEMM for that batch
  for (int b = 0; b < 4; ++b) {
    split_x_t<<<dim3(256, 8), blk, 0, stream>>>(x + (size_t)b * 256 * GN, xt_h, xt_l);
    gemm_mfma<768, true, false><<<dim3(768), blk, 0, stream>>>(
        wh1, wl1, xt_h, xt_l, qkv + (size_t)b * 768 * GN, 0);
  }
  // 3. kv + ksum reduction
  kv_ksum<<<dim3(16, 32), blk, 0, stream>>>(qkv, kvb, ksum);
  // 4. pool raw q (xt dead now; pools overlay it)
  pool_q<<<dim3(4096), blk, 0, stream>>>(qkv, qp2, qp4);
  // 5. pooled attention, in place
  pooled_attn<<<dim3(16, 32), blk, 0, stream>>>(qp2, kvb, ksum, 4096);
  pooled_attn<<<dim3(4, 32), blk, 0, stream>>>(qp4, kvb, ksum, 1024);
  // 6. fused scale-1 + upsample + weighted sum -> pre (head-major bf16 hi/lo)
  fused_out<<<dim3(64, 32), blk, 0, stream>>>(qkv, kvb, ksum, qp2, qp4, swin,
                                              preh, prel, PBS);
  // 7. projection via split-bf16 MFMA (4 batches, stride PBS, head-major X)
  gemm_mfma<256, false, true><<<dim3(1024), blk, 0, stream>>>(wh2, wl2, preh, prel, out, PBS);
}

// Round 6
// 439.694 us; speedup vs baseline: 1.5299x; 1.0657x over previous
//
#include <hip/hip_runtime.h>
#include <cstdint>
#include <cstddef>

#define GN 16384              // pixels per image (128*128)
#define QK_SCALE 0.17677669529663687f   // 32^-0.5

typedef __attribute__((ext_vector_type(8))) __bf16 bf16x8;
typedef __attribute__((ext_vector_type(4))) float f32x4;
typedef __attribute__((ext_vector_type(8))) unsigned short us8;
typedef __attribute__((ext_vector_type(4))) unsigned short us4;

__device__ __forceinline__ float qk_act(float z) {
  return z > 0.0f ? z + 1.0f : __expf(z);   // elu(z)+1
}

__device__ __forceinline__ unsigned short f2bf_rn(float v) {
  union { float f; unsigned u; } a; a.f = v;
  unsigned u = a.u;
  unsigned r = u + 0x7fffu + ((u >> 16) & 1u);
  return (unsigned short)(r >> 16);
}
__device__ __forceinline__ float bf2f(unsigned short h) {
  union { unsigned u; float f; } a; a.u = ((unsigned)h) << 16; return a.f;
}

#define GLLDS(SRC, DST) __builtin_amdgcn_global_load_lds( \
    (const __attribute__((address_space(1))) void*)(SRC), \
    (__attribute__((address_space(3))) void*)(DST), 16, 0, 0)

// ---------------------------------------------------------------------------
// Split a weight matrix (row-major [m][k]) into bf16 hi/lo.
// ---------------------------------------------------------------------------
__global__ __launch_bounds__(256) void split_w(
    const float* __restrict__ in, unsigned short* __restrict__ h,
    unsigned short* __restrict__ l, int n4)
{
  int i = blockIdx.x * 256 + threadIdx.x;
  if (i >= n4) return;
  float4 v = ((const float4*)in)[i];
  us4 vh, vl;
  vh[0] = f2bf_rn(v.x); vl[0] = f2bf_rn(v.x - bf2f(vh[0]));
  vh[1] = f2bf_rn(v.y); vl[1] = f2bf_rn(v.y - bf2f(vh[1]));
  vh[2] = f2bf_rn(v.z); vl[2] = f2bf_rn(v.z - bf2f(vh[2]));
  vh[3] = f2bf_rn(v.w); vl[3] = f2bf_rn(v.w - bf2f(vh[3]));
  ((us4*)h)[i] = vh;
  ((us4*)l)[i] = vl;
}

// ---------------------------------------------------------------------------
// Transpose + split one batch (blockIdx.z selects batch within group):
// x [256][GN] f32 -> xh/xl [z][GN][256] bf16.
// ---------------------------------------------------------------------------
__global__ __launch_bounds__(256) void split_x_t(
    const float* __restrict__ xb, unsigned short* __restrict__ xh,
    unsigned short* __restrict__ xl)
{
  __shared__ float ts[32][65];
  const int t  = threadIdx.x;
  const int n0 = blockIdx.x * 64;
  const int c0 = blockIdx.y * 32;
  const int z  = blockIdx.z;
  const float* src0 = xb + (size_t)z * 256 * GN;
  unsigned short* xho = xh + (size_t)z * GN * 256;
  unsigned short* xlo = xl + (size_t)z * GN * 256;
  {
    const int c  = t >> 3;
    const int nc = (t & 7) * 8;
    const float* src = src0 + ((size_t)(c0 + c)) * GN + n0 + nc;
    float4 v0 = *(const float4*)src;
    float4 v1 = *(const float4*)(src + 4);
    ts[c][nc + 0] = v0.x; ts[c][nc + 1] = v0.y; ts[c][nc + 2] = v0.z; ts[c][nc + 3] = v0.w;
    ts[c][nc + 4] = v1.x; ts[c][nc + 5] = v1.y; ts[c][nc + 6] = v1.z; ts[c][nc + 7] = v1.w;
  }
  __syncthreads();
  {
    const int n  = t & 63;
    const int cg = (t >> 6) * 8;
    us8 vh, vl;
#pragma unroll
    for (int j = 0; j < 8; ++j) {
      float v = ts[cg + j][n];
      unsigned short hh = f2bf_rn(v);
      vh[j] = hh;
      vl[j] = f2bf_rn(v - bf2f(hh));
    }
    size_t off = ((size_t)(n0 + n)) * 256 + c0 + cg;
    *(us8*)(xho + off) = vh;
    *(us8*)(xlo + off) = vl;
  }
}

// ---------------------------------------------------------------------------
// Split-bf16 MFMA GEMM:  Out[b][m][n] = sum_k W[m][k] * X[b][n][k]
// HEADMAJ=false: X rows are [n][256] contiguous.
// HEADMAJ=true : X is [head][GN][32] per batch (head = k>>5).
// 128x128 tile, BK=32, 4 waves, 16x16x32 MFMA, m97 structure.
// KACT: apply elu(v*scale)+1 to rows [256,512).
// ---------------------------------------------------------------------------
template<int M, bool KACT, bool HEADMAJ>
__global__ __launch_bounds__(256) void gemm_mfma(
    const unsigned short* __restrict__ Wh, const unsigned short* __restrict__ Wl,
    const unsigned short* __restrict__ Xh, const unsigned short* __restrict__ Xl,
    float* __restrict__ Out, size_t XBS)
{
  constexpr int MT = M / 128;
  __shared__ __align__(16) char lds[32768];   // Ah | Al | Bh | Bl (8KB each)
  const int tid = threadIdx.x;
  const int w = tid >> 6;
  const int l = tid & 63;

  // XCD chunk swizzle (grid divisible by 8)
  const int per  = gridDim.x >> 3;
  const int bid  = blockIdx.x;
  const int lbid = (bid & 7) * per + (bid >> 3);
  const int mt = lbid % MT;                 // fastest: M-tiles share the X slab
  const int nt = (lbid / MT) & 127;
  const int b  = lbid / (MT * 128);

  const int m0 = mt * 128;
  const int n0 = nt * 128;

  const unsigned short* xh_b = Xh + (size_t)b * XBS;
  const unsigned short* xl_b = Xl + (size_t)b * XBS;

  f32x4 acc[4][4];
  const f32x4 zz = {0.f, 0.f, 0.f, 0.f};
#pragma unroll
  for (int i = 0; i < 4; ++i)
#pragma unroll
    for (int j = 0; j < 4; ++j) acc[i][j] = zz;

  const int wm = w >> 1, wn = w & 1;
  const int lr = l & 15, lk = l >> 4;
  const int ra  = wm * 64 + lr;
  const int rb  = wn * 64 + lr;
  const int cxa = (lk ^ (lr & 3)) << 4;     // swizzled 16B-chunk byte offset

  for (int kt = 0; kt < 256; kt += 32) {
    // ---- stage 32KB via global_load_lds (16B/lane, XOR-swizzled source) ----
#pragma unroll
    for (int j = 0; j < 2; ++j) {
      const int r0 = w * 32 + j * 16;       // wave-uniform
      const int r  = r0 + (l >> 2);
      const int lc = (((l & 3) ^ (r & 3)) << 3);   // logical elem offset in row
      const size_t wrow = (size_t)(m0 + r) * 256 + kt + lc;
      const size_t xrow = HEADMAJ
          ? (size_t)(kt >> 5) * ((size_t)GN * 32) + (size_t)(n0 + r) * 32 + lc
          : (size_t)(n0 + r) * 256 + kt + lc;
      GLLDS(Wh + wrow,   lds + 0     + r0 * 64);
      GLLDS(Wl + wrow,   lds + 8192  + r0 * 64);
      GLLDS(xh_b + xrow, lds + 16384 + r0 * 64);
      GLLDS(xl_b + xrow, lds + 24576 + r0 * 64);
    }
    __syncthreads();

    // ---- fragments (ds_read_b128, contiguous k-map, inverse swizzle) ----
    bf16x8 ah[4], al[4], bh[4], bl[4];
#pragma unroll
    for (int s = 0; s < 4; ++s) {
      const int oa = (ra + s * 16) * 64 + cxa;
      const int ob = (rb + s * 16) * 64 + cxa;
      ah[s] = *(const bf16x8*)(lds + 0     + oa);
      al[s] = *(const bf16x8*)(lds + 8192  + oa);
      bh[s] = *(const bf16x8*)(lds + 16384 + ob);
      bl[s] = *(const bf16x8*)(lds + 24576 + ob);
    }
    // ---- 3-term split MFMA: hh + hl + lh ----
#pragma unroll
    for (int ms = 0; ms < 4; ++ms)
#pragma unroll
      for (int ns = 0; ns < 4; ++ns) {
        acc[ms][ns] = __builtin_amdgcn_mfma_f32_16x16x32_bf16(ah[ms], bh[ns], acc[ms][ns], 0, 0, 0);
        acc[ms][ns] = __builtin_amdgcn_mfma_f32_16x16x32_bf16(ah[ms], bl[ns], acc[ms][ns], 0, 0, 0);
        acc[ms][ns] = __builtin_amdgcn_mfma_f32_16x16x32_bf16(al[ms], bh[ns], acc[ms][ns], 0, 0, 0);
      }
    __syncthreads();
  }

  // ---- epilogue: C/D map col=lane&15, row=(lane>>4)*4+reg ----
  const bool act = KACT && (m0 >= 256 && m0 < 512);
#pragma unroll
  for (int ms = 0; ms < 4; ++ms)
#pragma unroll
    for (int ns = 0; ns < 4; ++ns) {
      const int m = m0 + wm * 64 + ms * 16 + lk * 4;
      const int n = n0 + wn * 64 + ns * 16 + lr;
      float* op = Out + ((size_t)b * M + m) * GN + n;
#pragma unroll
      for (int r = 0; r < 4; ++r) {
        float v = acc[ms][ns][r];
        if (act) v = qk_act(v * QK_SCALE);
        op[(size_t)r * GN] = v;
      }
    }
}

// ---------------------------------------------------------------------------
// kv[bh][d][e] = sum_n k'[bh][d][n] * v[bh][e][n];  ksum[bh][d] = sum_n k'.
// Grid (64 chunks of 256 px, 32 bh) for occupancy (was 16 chunks -> 17% occ).
// ---------------------------------------------------------------------------
__global__ __launch_bounds__(256) void kv_ksum(
    const float* __restrict__ qkv, float* __restrict__ kvbuf,
    float* __restrict__ ksumbuf)
{
  __shared__ __align__(16) float ksh[32][68];
  __shared__ __align__(16) float vsh[32][68];
  const int tid = threadIdx.x;
  const int bh = blockIdx.y;
  const int b = bh >> 3;
  const int head = bh & 7;
  const int dd = tid & 31;
  const int eg = tid >> 5;

  const float* Kb = qkv + ((size_t)b * 768 + 256 + head * 32) * GN;
  const float* Vb = qkv + ((size_t)b * 768 + 512 + head * 32) * GN;
  const int pbase = blockIdx.x * 256;

  float acc[4] = {0.f, 0.f, 0.f, 0.f};
  float ksacc = 0.f;

  for (int st = 0; st < 256; st += 64) {
    const int p0 = pbase + st;
#pragma unroll
    for (int t = 0; t < 2; ++t) {
      int idx = t * 256 + tid;
      int ch = idx >> 4;
      int c4 = idx & 15;
      *(float4*)&ksh[ch][c4 * 4] = *(const float4*)(Kb + (size_t)ch * GN + p0 + c4 * 4);
      *(float4*)&vsh[ch][c4 * 4] = *(const float4*)(Vb + (size_t)ch * GN + p0 + c4 * 4);
    }
    __syncthreads();
#pragma unroll
    for (int pg = 0; pg < 16; ++pg) {
      float4 kd = *(const float4*)&ksh[dd][pg * 4];
#pragma unroll
      for (int j = 0; j < 4; ++j) {
        float4 vv = *(const float4*)&vsh[eg * 4 + j][pg * 4];
        acc[j] += kd.x * vv.x + kd.y * vv.y + kd.z * vv.z + kd.w * vv.w;
      }
      if (eg == 0) ksacc += kd.x + kd.y + kd.z + kd.w;
    }
    __syncthreads();
  }

  float* kvp = kvbuf + ((size_t)bh * 32 + dd) * 32 + eg * 4;
#pragma unroll
  for (int j = 0; j < 4; ++j) atomicAdd(kvp + j, acc[j]);
  if (eg == 0) atomicAdd(ksumbuf + bh * 32 + dd, ksacc);
}

// ---------------------------------------------------------------------------
// Pool raw q: 2x2 -> qp2 [B][256][4096], 4x4 -> qp4 [B][256][1024]
// ---------------------------------------------------------------------------
__global__ __launch_bounds__(256) void pool_q(
    const float* __restrict__ qkv, float* __restrict__ qp2,
    float* __restrict__ qp4)
{
  const int g = blockIdx.x * 256 + threadIdx.x;
  const int x4 = g & 31;
  const int y4 = (g >> 5) & 31;
  const int bc = g >> 10;
  const int b = bc >> 8;
  const int c = bc & 255;
  const float* src = qkv + ((size_t)b * 768 + c) * GN + (y4 * 4) * 128 + x4 * 4;
  float4 r0 = *(const float4*)(src);
  float4 r1 = *(const float4*)(src + 128);
  float4 r2 = *(const float4*)(src + 256);
  float4 r3 = *(const float4*)(src + 384);
  float m00 = (r0.x + r0.y + r1.x + r1.y) * 0.25f;
  float m01 = (r0.z + r0.w + r1.z + r1.w) * 0.25f;
  float m10 = (r2.x + r2.y + r3.x + r3.y) * 0.25f;
  float m11 = (r2.z + r2.w + r3.z + r3.w) * 0.25f;
  float m4 = (m00 + m01 + m10 + m11) * 0.25f;
  float* p2 = qp2 + (size_t)bc * 4096 + (y4 * 2) * 64 + x4 * 2;
  float2 wa = {m00, m01};
  float2 wb = {m10, m11};
  *(float2*)p2 = wa;
  *(float2*)(p2 + 64) = wb;
  qp4[(size_t)bc * 1024 + y4 * 32 + x4] = m4;
}

// ---------------------------------------------------------------------------
// Pooled attention IN-PLACE: qp[p] <- (act(qp*scale) @ kv) / max(..., eps).
// ---------------------------------------------------------------------------
__global__ __launch_bounds__(256) void pooled_attn(
    float* qp, const float* __restrict__ kvbuf,
    const float* __restrict__ ksumbuf, int Np)
{
  __shared__ __align__(16) float kv_s[32][32];
  __shared__ float ks_s[32];
  const int tid = threadIdx.x;
  const int bh = blockIdx.y;
  const int b = bh >> 3;
  const int head = bh & 7;
  const int p = blockIdx.x * 256 + tid;

  const float* kvb = kvbuf + (size_t)bh * 1024;
#pragma unroll
  for (int t = 0; t < 4; ++t) ((float*)kv_s)[t * 256 + tid] = kvb[t * 256 + tid];
  if (tid < 32) ks_s[tid] = ksumbuf[bh * 32 + tid];
  __syncthreads();

  float* q0 = qp + ((size_t)(b * 256 + head * 32)) * Np + p;
  float qa[32];
#pragma unroll
  for (int dd = 0; dd < 32; ++dd) qa[dd] = qk_act(q0[(size_t)dd * Np] * QK_SCALE);

  float o1[32];
#pragma unroll
  for (int e = 0; e < 32; ++e) o1[e] = 0.f;
  float norm = 0.f;
#pragma unroll
  for (int dd = 0; dd < 32; ++dd) {
    float qv = qa[dd];
    norm += qv * ks_s[dd];
#pragma unroll
    for (int e4 = 0; e4 < 8; ++e4) {
      float4 kvv = *(const float4*)&kv_s[dd][e4 * 4];
      o1[e4 * 4 + 0] += qv * kvv.x;
      o1[e4 * 4 + 1] += qv * kvv.y;
      o1[e4 * 4 + 2] += qv * kvv.z;
      o1[e4 * 4 + 3] += qv * kvv.w;
    }
  }
  norm = fmaxf(norm, 1e-6f);
  float inv1 = 1.0f / norm;
#pragma unroll
  for (int e = 0; e < 32; ++e) q0[(size_t)e * Np] = o1[e] * inv1;
}

// ---------------------------------------------------------------------------
// Fused final: scale-1 attention + bilinear upsample of pooled outputs
// (staged in LDS), softmax-weighted; emits proj input HEAD-MAJOR
// [b][head][n][32] bf16 hi/lo -> fully coalesced 64B/thread writes.
// Block: one (row-pair m, bh): 256 px, 2 image rows {2m, 2m+1}.
// ---------------------------------------------------------------------------
__global__ __launch_bounds__(256) void fused_out(
    const float* __restrict__ qkv, const float* __restrict__ kvbuf,
    const float* __restrict__ ksumbuf, const float* __restrict__ ao2,
    const float* __restrict__ ao4, const float* __restrict__ swin,
    unsigned short* __restrict__ preh, unsigned short* __restrict__ prel,
    size_t PBS)
{
  __shared__ __align__(16) float kv_s[32][32];     //  4 KB
  __shared__ float ks_s[32];
  __shared__ __align__(16) float a2_s[3][32][64];  // 24 KB: [row][e][x]
  __shared__ __align__(16) float a4_s[3][32][32];  // 12 KB
  const int tid = threadIdx.x;
  const int m  = blockIdx.x;            // row-pair index, y in {2m, 2m+1}
  const int bh = blockIdx.y;
  const int b = bh >> 3;
  const int head = bh & 7;
  const int n = m * 256 + tid;

  const float* kvb = kvbuf + (size_t)bh * 1024;
#pragma unroll
  for (int t = 0; t < 4; ++t) ((float*)kv_s)[t * 256 + tid] = kvb[t * 256 + tid];
  if (tid < 32) ks_s[tid] = ksumbuf[bh * 32 + tid];

  const float* a2 = ao2 + ((size_t)(b * 256 + head * 32)) * 4096;
  const float* a4 = ao4 + ((size_t)(b * 256 + head * 32)) * 1024;
  const int p = m >> 1;
  int r2[3], r4[3];
#pragma unroll
  for (int j = 0; j < 3; ++j) {
    int a = m - 1 + j; r2[j] = a < 0 ? 0 : (a > 63 ? 63 : a);
    int c = p - 1 + j; r4[j] = c < 0 ? 0 : (c > 31 ? 31 : c);
  }
  // stage ao2 rows {m-1,m,m+1}: 1536 float4, coalesced
#pragma unroll
  for (int t = 0; t < 6; ++t) {
    int fidx = t * 256 + tid;
    int x4 = fidx & 15, e = (fidx >> 4) & 31, j = fidx >> 9;
    *(float4*)&a2_s[j][e][x4 * 4] =
        *(const float4*)(a2 + (size_t)e * 4096 + r2[j] * 64 + x4 * 4);
  }
  // stage ao4 rows {p-1,p,p+1}: 768 float4
#pragma unroll
  for (int t = 0; t < 3; ++t) {
    int fidx = t * 256 + tid;
    int x4 = fidx & 7, e = (fidx >> 3) & 31, j = fidx >> 8;
    *(float4*)&a4_s[j][e][x4 * 4] =
        *(const float4*)(a4 + (size_t)e * 1024 + r4[j] * 32 + x4 * 4);
  }
  __syncthreads();

  float s0 = swin[0], s1 = swin[1], s2 = swin[2];
  float mx = fmaxf(s0, fmaxf(s1, s2));
  float ex0 = __expf(s0 - mx), ex1 = __expf(s1 - mx), ex2 = __expf(s2 - mx);
  float sinv = 1.0f / (ex0 + ex1 + ex2);
  float sw0 = ex0 * sinv, sw1 = ex1 * sinv, sw2 = ex2 * sinv;

  // ---- scale-1 linear attention for this pixel ----
  const float* q0 = qkv + ((size_t)b * 768 + head * 32) * GN + n;
  float qa[32];
#pragma unroll
  for (int dd = 0; dd < 32; ++dd) qa[dd] = qk_act(q0[(size_t)dd * GN] * QK_SCALE);

  float o1[32];
#pragma unroll
  for (int e = 0; e < 32; ++e) o1[e] = 0.f;
  float norm = 0.f;
#pragma unroll
  for (int dd = 0; dd < 32; ++dd) {
    float qv = qa[dd];
    norm += qv * ks_s[dd];
#pragma unroll
    for (int e4 = 0; e4 < 8; ++e4) {
      float4 kvv = *(const float4*)&kv_s[dd][e4 * 4];
      o1[e4 * 4 + 0] += qv * kvv.x;
      o1[e4 * 4 + 1] += qv * kvv.y;
      o1[e4 * 4 + 2] += qv * kvv.z;
      o1[e4 * 4 + 3] += qv * kvv.w;
    }
  }
  norm = fmaxf(norm, 1e-6f);
  float inv1 = 1.0f / norm;

  // ---- bilinear params (closed form; half-pixel mapping) ----
  const int yb = tid >> 7;                  // 0/1 -> y = 2m + yb
  const int x  = n & 127;
  const int j2 = yb;
  const float wy2 = yb ? 0.25f : 0.75f;
  const int xu = x >> 1;
  const int x20 = xu - 1 + (x & 1);
  const float wx2 = (x & 1) ? 0.25f : 0.75f;
  const int x20c = x20 < 0 ? 0 : x20;
  const int x21c = (x20 + 1) < 63 ? (x20 + 1) : 63;
  const int j4 = m & 1;
  const float wy4 = (0.625f - 0.5f * (float)(m & 1)) + 0.25f * (float)yb;
  const int xq = x >> 2, xr = x & 3;
  const int x40 = xq - 1 + (xr >> 1);
  const float wx4 = ((xr & 1) ? 0.875f : 0.625f) - ((xr >> 1) ? 0.5f : 0.0f);
  const int x40c = x40 < 0 ? 0 : x40;
  const int x41c = (x40 + 1) < 31 ? (x40 + 1) : 31;

  const float wy2i = 1.f - wy2, wx2i = 1.f - wx2;
  const float wy4i = 1.f - wy4, wx4i = 1.f - wx4;

  // ---- combine + write head-major [head][n][32] (64B contig per thread) ----
  unsigned short* ph = preh + (size_t)b * PBS + (size_t)head * (GN * 32) + (size_t)n * 32;
  unsigned short* pl = prel + (size_t)b * PBS + (size_t)head * (GN * 32) + (size_t)n * 32;

#pragma unroll
  for (int t4 = 0; t4 < 4; ++t4) {
    us8 vh, vl;
#pragma unroll
    for (int j = 0; j < 8; ++j) {
      const int e = t4 * 8 + j;
      float u2 = wy2i * (wx2i * a2_s[j2][e][x20c] + wx2 * a2_s[j2][e][x21c])
               + wy2  * (wx2i * a2_s[j2 + 1][e][x20c] + wx2 * a2_s[j2 + 1][e][x21c]);
      float u4 = wy4i * (wx4i * a4_s[j4][e][x40c] + wx4 * a4_s[j4][e][x41c])
               + wy4  * (wx4i * a4_s[j4 + 1][e][x40c] + wx4 * a4_s[j4 + 1][e][x41c]);
      float val = sw0 * o1[e] * inv1 + sw1 * u2 + sw2 * u4;
      unsigned short hh = f2bf_rn(val);
      vh[j] = hh;
      vl[j] = f2bf_rn(val - bf2f(hh));
    }
    *(us8*)(ph + t4 * 8) = vh;
    *(us8*)(pl + t4 * 8) = vl;
  }
}

// ---------------------------------------------------------------------------
extern "C" void kernel_launch(void* const* d_in, const int* in_sizes, int n_in,
                              void* d_out, int out_size, void* d_ws, size_t ws_size,
                              hipStream_t stream) {
  const float* x     = (const float*)d_in[0];
  const float* Wqkv  = (const float*)d_in[1];
  const float* Wproj = (const float*)d_in[2];
  const float* swin  = (const float*)d_in[3];
  float* out = (float*)d_out;
  float* ws  = (float*)d_ws;

  // ---- workspace layout (floats); total 59,016,192 f = 236.1 MB ----
  float* qkv = ws;                                   // 50,331,648 f
  float* xtreg = ws + (size_t)50331648;              // 8,388,608 f region
  // xt: 2-batch transposed split x; pools overlay after xt is dead
  unsigned short* xt_h = (unsigned short*)xtreg;     // 2 x 4,194,304 us
  unsigned short* xt_l = xt_h + (size_t)8388608;     // 2 x 4,194,304 us
  float* qp2 = xtreg;                                // 4,194,304 f (in-place ao2)
  float* qp4 = xtreg + (size_t)4194304;              // 1,048,576 f (in-place ao4)
  float* kvb  = xtreg + (size_t)8388608;             // 32,768 f
  float* ksum = kvb + 32768;                         // 1,024 f
  unsigned short* wh1 = (unsigned short*)(ksum + 1024);  // 196,608 us
  unsigned short* wl1 = wh1 + 196608;                // 196,608 us
  unsigned short* wh2 = wl1 + 196608;                // 65,536 us
  unsigned short* wl2 = wh2 + 65536;                 // 65,536 us
  // pre (proj input) overlaid on dead v region of qkv; head-major bf16 hi/lo
  unsigned short* preh = (unsigned short*)qkv + (size_t)1024 * GN;
  unsigned short* prel = (unsigned short*)qkv + (size_t)1280 * GN;
  const size_t PBS = (size_t)1536 * GN;              // per-batch stride (ushorts)

  hipMemsetAsync(kvb, 0, (32768 + 1024) * sizeof(float), stream);

  dim3 blk(256);
  // 0. weight splits
  split_w<<<dim3(192), blk, 0, stream>>>(Wqkv, wh1, wl1, 49152);
  split_w<<<dim3(64),  blk, 0, stream>>>(Wproj, wh2, wl2, 16384);
  // 1+2. per 2-batch group: transpose+split both slabs, then one 1536-block GEMM
  for (int g = 0; g < 2; ++g) {
    split_x_t<<<dim3(256, 8, 2), blk, 0, stream>>>(
        x + (size_t)g * 2 * 256 * GN, xt_h, xt_l);
    gemm_mfma<768, true, false><<<dim3(1536), blk, 0, stream>>>(
        wh1, wl1, xt_h, xt_l, qkv + (size_t)g * 2 * 768 * GN, (size_t)GN * 256);
  }
  // 3. kv + ksum reduction (64 chunks -> 2048 blocks, 8/CU)
  kv_ksum<<<dim3(64, 32), blk, 0, stream>>>(qkv, kvb, ksum);
  // 4. pool raw q (xt dead now; pools overlay it)
  pool_q<<<dim3(4096), blk, 0, stream>>>(qkv, qp2, qp4);
  // 5. pooled attention, in place
  pooled_attn<<<dim3(16, 32), blk, 0, stream>>>(qp2, kvb, ksum, 4096);
  pooled_attn<<<dim3(4, 32), blk, 0, stream>>>(qp4, kvb, ksum, 1024);
  // 6. fused scale-1 + upsample + weighted sum -> pre (head-major bf16 hi/lo)
  fused_out<<<dim3(64, 32), blk, 0, stream>>>(qkv, kvb, ksum, qp2, qp4, swin,
                                              preh, prel, PBS);
  // 7. projection via split-bf16 MFMA (4 batches, stride PBS, head-major X)
  gemm_mfma<256, false, true><<<dim3(1024), blk, 0, stream>>>(wh2, wl2, preh, prel, out, PBS);
}

// Round 7
// 395.700 us; speedup vs baseline: 1.7000x; 1.1112x over previous
//
#include <hip/hip_runtime.h>
#include <cstdint>
#include <cstddef>

#define GN 16384              // pixels per image (128*128)
#define QK_SCALE 0.17677669529663687f   // 32^-0.5

typedef __attribute__((ext_vector_type(8))) __bf16 bf16x8;
typedef __attribute__((ext_vector_type(4))) float f32x4;
typedef __attribute__((ext_vector_type(8))) unsigned short us8;
typedef __attribute__((ext_vector_type(4))) unsigned short us4;

__device__ __forceinline__ float qk_act(float z) {
  return z > 0.0f ? z + 1.0f : __expf(z);   // elu(z)+1
}

__device__ __forceinline__ unsigned short f2bf_rn(float v) {
  union { float f; unsigned u; } a; a.f = v;
  unsigned u = a.u;
  unsigned r = u + 0x7fffu + ((u >> 16) & 1u);
  return (unsigned short)(r >> 16);
}
__device__ __forceinline__ float bf2f(unsigned short h) {
  union { unsigned u; float f; } a; a.u = ((unsigned)h) << 16; return a.f;
}

#define GLLDS(SRC, DST) __builtin_amdgcn_global_load_lds( \
    (const __attribute__((address_space(1))) void*)(SRC), \
    (__attribute__((address_space(3))) void*)(DST), 16, 0, 0)

// ---------------------------------------------------------------------------
// Split a weight matrix (row-major [m][k]) into bf16 hi/lo.
// ---------------------------------------------------------------------------
__global__ __launch_bounds__(256) void split_w(
    const float* __restrict__ in, unsigned short* __restrict__ h,
    unsigned short* __restrict__ l, int n4)
{
  int i = blockIdx.x * 256 + threadIdx.x;
  if (i >= n4) return;
  float4 v = ((const float4*)in)[i];
  us4 vh, vl;
  vh[0] = f2bf_rn(v.x); vl[0] = f2bf_rn(v.x - bf2f(vh[0]));
  vh[1] = f2bf_rn(v.y); vl[1] = f2bf_rn(v.y - bf2f(vh[1]));
  vh[2] = f2bf_rn(v.z); vl[2] = f2bf_rn(v.z - bf2f(vh[2]));
  vh[3] = f2bf_rn(v.w); vl[3] = f2bf_rn(v.w - bf2f(vh[3]));
  ((us4*)h)[i] = vh;
  ((us4*)l)[i] = vl;
}

// ---------------------------------------------------------------------------
// Transpose + split one batch (blockIdx.z selects batch within group):
// x [256][GN] f32 -> xh/xl [z][GN][256] bf16.
// ---------------------------------------------------------------------------
__global__ __launch_bounds__(256) void split_x_t(
    const float* __restrict__ xb, unsigned short* __restrict__ xh,
    unsigned short* __restrict__ xl)
{
  __shared__ float ts[32][65];
  const int t  = threadIdx.x;
  const int n0 = blockIdx.x * 64;
  const int c0 = blockIdx.y * 32;
  const int z  = blockIdx.z;
  const float* src0 = xb + (size_t)z * 256 * GN;
  unsigned short* xho = xh + (size_t)z * GN * 256;
  unsigned short* xlo = xl + (size_t)z * GN * 256;
  {
    const int c  = t >> 3;
    const int nc = (t & 7) * 8;
    const float* src = src0 + ((size_t)(c0 + c)) * GN + n0 + nc;
    float4 v0 = *(const float4*)src;
    float4 v1 = *(const float4*)(src + 4);
    ts[c][nc + 0] = v0.x; ts[c][nc + 1] = v0.y; ts[c][nc + 2] = v0.z; ts[c][nc + 3] = v0.w;
    ts[c][nc + 4] = v1.x; ts[c][nc + 5] = v1.y; ts[c][nc + 6] = v1.z; ts[c][nc + 7] = v1.w;
  }
  __syncthreads();
  {
    const int n  = t & 63;
    const int cg = (t >> 6) * 8;
    us8 vh, vl;
#pragma unroll
    for (int j = 0; j < 8; ++j) {
      float v = ts[cg + j][n];
      unsigned short hh = f2bf_rn(v);
      vh[j] = hh;
      vl[j] = f2bf_rn(v - bf2f(hh));
    }
    size_t off = ((size_t)(n0 + n)) * 256 + c0 + cg;
    *(us8*)(xho + off) = vh;
    *(us8*)(xlo + off) = vl;
  }
}

// ---------------------------------------------------------------------------
// Split-bf16 MFMA GEMM:  Out[b][m][n] = sum_k W[m][k] * X[b][n][k]
// HEADMAJ=false: X rows are [n][256] contiguous.
// HEADMAJ=true : X is [head][GN][32] per batch (head = k>>5).
// 128x128 tile, BK=32, 4 waves, 16x16x32 MFMA, m97 structure.
// KACT: apply elu(v*scale)+1 to rows [256,512).
// ---------------------------------------------------------------------------
template<int M, bool KACT, bool HEADMAJ>
__global__ __launch_bounds__(256) void gemm_mfma(
    const unsigned short* __restrict__ Wh, const unsigned short* __restrict__ Wl,
    const unsigned short* __restrict__ Xh, const unsigned short* __restrict__ Xl,
    float* __restrict__ Out, size_t XBS)
{
  constexpr int MT = M / 128;
  __shared__ __align__(16) char lds[32768];   // Ah | Al | Bh | Bl (8KB each)
  const int tid = threadIdx.x;
  const int w = tid >> 6;
  const int l = tid & 63;

  // XCD chunk swizzle (grid divisible by 8)
  const int per  = gridDim.x >> 3;
  const int bid  = blockIdx.x;
  const int lbid = (bid & 7) * per + (bid >> 3);
  const int mt = lbid % MT;                 // fastest: M-tiles share the X slab
  const int nt = (lbid / MT) & 127;
  const int b  = lbid / (MT * 128);

  const int m0 = mt * 128;
  const int n0 = nt * 128;

  const unsigned short* xh_b = Xh + (size_t)b * XBS;
  const unsigned short* xl_b = Xl + (size_t)b * XBS;

  f32x4 acc[4][4];
  const f32x4 zz = {0.f, 0.f, 0.f, 0.f};
#pragma unroll
  for (int i = 0; i < 4; ++i)
#pragma unroll
    for (int j = 0; j < 4; ++j) acc[i][j] = zz;

  const int wm = w >> 1, wn = w & 1;
  const int lr = l & 15, lk = l >> 4;
  const int ra  = wm * 64 + lr;
  const int rb  = wn * 64 + lr;
  const int cxa = (lk ^ (lr & 3)) << 4;     // swizzled 16B-chunk byte offset

  for (int kt = 0; kt < 256; kt += 32) {
    // ---- stage 32KB via global_load_lds (16B/lane, XOR-swizzled source) ----
#pragma unroll
    for (int j = 0; j < 2; ++j) {
      const int r0 = w * 32 + j * 16;       // wave-uniform
      const int r  = r0 + (l >> 2);
      const int lc = (((l & 3) ^ (r & 3)) << 3);   // logical elem offset in row
      const size_t wrow = (size_t)(m0 + r) * 256 + kt + lc;
      const size_t xrow = HEADMAJ
          ? (size_t)(kt >> 5) * ((size_t)GN * 32) + (size_t)(n0 + r) * 32 + lc
          : (size_t)(n0 + r) * 256 + kt + lc;
      GLLDS(Wh + wrow,   lds + 0     + r0 * 64);
      GLLDS(Wl + wrow,   lds + 8192  + r0 * 64);
      GLLDS(xh_b + xrow, lds + 16384 + r0 * 64);
      GLLDS(xl_b + xrow, lds + 24576 + r0 * 64);
    }
    __syncthreads();

    // ---- fragments (ds_read_b128, contiguous k-map, inverse swizzle) ----
    bf16x8 ah[4], al[4], bh[4], bl[4];
#pragma unroll
    for (int s = 0; s < 4; ++s) {
      const int oa = (ra + s * 16) * 64 + cxa;
      const int ob = (rb + s * 16) * 64 + cxa;
      ah[s] = *(const bf16x8*)(lds + 0     + oa);
      al[s] = *(const bf16x8*)(lds + 8192  + oa);
      bh[s] = *(const bf16x8*)(lds + 16384 + ob);
      bl[s] = *(const bf16x8*)(lds + 24576 + ob);
    }
    // ---- 3-term split MFMA: hh + hl + lh ----
#pragma unroll
    for (int ms = 0; ms < 4; ++ms)
#pragma unroll
      for (int ns = 0; ns < 4; ++ns) {
        acc[ms][ns] = __builtin_amdgcn_mfma_f32_16x16x32_bf16(ah[ms], bh[ns], acc[ms][ns], 0, 0, 0);
        acc[ms][ns] = __builtin_amdgcn_mfma_f32_16x16x32_bf16(ah[ms], bl[ns], acc[ms][ns], 0, 0, 0);
        acc[ms][ns] = __builtin_amdgcn_mfma_f32_16x16x32_bf16(al[ms], bh[ns], acc[ms][ns], 0, 0, 0);
      }
    __syncthreads();
  }

  // ---- epilogue: C/D map col=lane&15, row=(lane>>4)*4+reg ----
  const bool act = KACT && (m0 >= 256 && m0 < 512);
#pragma unroll
  for (int ms = 0; ms < 4; ++ms)
#pragma unroll
    for (int ns = 0; ns < 4; ++ns) {
      const int m = m0 + wm * 64 + ms * 16 + lk * 4;
      const int n = n0 + wn * 64 + ns * 16 + lr;
      float* op = Out + ((size_t)b * M + m) * GN + n;
#pragma unroll
      for (int r = 0; r < 4; ++r) {
        float v = acc[ms][ns][r];
        if (act) v = qk_act(v * QK_SCALE);
        op[(size_t)r * GN] = v;
      }
    }
}

// ---------------------------------------------------------------------------
// Stage 1: per-(chunk,bh) partial kv/ksum, NO atomics.
// part[(chunk*32+bh)*1056 + d*32+e] = sum over 256 px; [+1024+d] = ksum part.
// ---------------------------------------------------------------------------
__global__ __launch_bounds__(256) void kv_ksum(
    const float* __restrict__ qkv, float* __restrict__ part)
{
  __shared__ __align__(16) float ksh[32][68];
  __shared__ __align__(16) float vsh[32][68];
  const int tid = threadIdx.x;
  const int bh = blockIdx.y;
  const int b = bh >> 3;
  const int head = bh & 7;
  const int dd = tid & 31;
  const int eg = tid >> 5;

  const float* Kb = qkv + ((size_t)b * 768 + 256 + head * 32) * GN;
  const float* Vb = qkv + ((size_t)b * 768 + 512 + head * 32) * GN;
  const int pbase = blockIdx.x * 256;

  float acc[4] = {0.f, 0.f, 0.f, 0.f};
  float ksacc = 0.f;

  for (int st = 0; st < 256; st += 64) {
    const int p0 = pbase + st;
#pragma unroll
    for (int t = 0; t < 2; ++t) {
      int idx = t * 256 + tid;
      int ch = idx >> 4;
      int c4 = idx & 15;
      *(float4*)&ksh[ch][c4 * 4] = *(const float4*)(Kb + (size_t)ch * GN + p0 + c4 * 4);
      *(float4*)&vsh[ch][c4 * 4] = *(const float4*)(Vb + (size_t)ch * GN + p0 + c4 * 4);
    }
    __syncthreads();
#pragma unroll
    for (int pg = 0; pg < 16; ++pg) {
      float4 kd = *(const float4*)&ksh[dd][pg * 4];
#pragma unroll
      for (int j = 0; j < 4; ++j) {
        float4 vv = *(const float4*)&vsh[eg * 4 + j][pg * 4];
        acc[j] += kd.x * vv.x + kd.y * vv.y + kd.z * vv.z + kd.w * vv.w;
      }
      if (eg == 0) ksacc += kd.x + kd.y + kd.z + kd.w;
    }
    __syncthreads();
  }

  float* pp = part + ((size_t)blockIdx.x * 32 + bh) * 1056;
  float4 av = {acc[0], acc[1], acc[2], acc[3]};
  *(float4*)(pp + dd * 32 + eg * 4) = av;
  if (eg == 0) pp[1024 + dd] = ksacc;
}

// ---------------------------------------------------------------------------
// Stage 2: reduce 64 chunk-partials -> kvbuf [bh][32][32], ksumbuf [bh][32].
// 33792 threads; per-c reads are wave-contiguous (coalesced).
// ---------------------------------------------------------------------------
__global__ __launch_bounds__(256) void kv_reduce(
    const float* __restrict__ part, float* __restrict__ kvbuf,
    float* __restrict__ ksumbuf)
{
  const int g = blockIdx.x * 256 + threadIdx.x;   // < 33792
  const int bh = g / 1056;
  const int idx = g - bh * 1056;
  float s = 0.f;
#pragma unroll 4
  for (int c = 0; c < 64; ++c) s += part[((size_t)c * 32 + bh) * 1056 + idx];
  if (idx < 1024) kvbuf[bh * 1024 + idx] = s;
  else            ksumbuf[bh * 32 + (idx - 1024)] = s;
}

// ---------------------------------------------------------------------------
// Pool raw q: 2x2 -> qp2 [B][256][4096], 4x4 -> qp4 [B][256][1024]
// ---------------------------------------------------------------------------
__global__ __launch_bounds__(256) void pool_q(
    const float* __restrict__ qkv, float* __restrict__ qp2,
    float* __restrict__ qp4)
{
  const int g = blockIdx.x * 256 + threadIdx.x;
  const int x4 = g & 31;
  const int y4 = (g >> 5) & 31;
  const int bc = g >> 10;
  const int b = bc >> 8;
  const int c = bc & 255;
  const float* src = qkv + ((size_t)b * 768 + c) * GN + (y4 * 4) * 128 + x4 * 4;
  float4 r0 = *(const float4*)(src);
  float4 r1 = *(const float4*)(src + 128);
  float4 r2 = *(const float4*)(src + 256);
  float4 r3 = *(const float4*)(src + 384);
  float m00 = (r0.x + r0.y + r1.x + r1.y) * 0.25f;
  float m01 = (r0.z + r0.w + r1.z + r1.w) * 0.25f;
  float m10 = (r2.x + r2.y + r3.x + r3.y) * 0.25f;
  float m11 = (r2.z + r2.w + r3.z + r3.w) * 0.25f;
  float m4 = (m00 + m01 + m10 + m11) * 0.25f;
  float* p2 = qp2 + (size_t)bc * 4096 + (y4 * 2) * 64 + x4 * 2;
  float2 wa = {m00, m01};
  float2 wb = {m10, m11};
  *(float2*)p2 = wa;
  *(float2*)(p2 + 64) = wb;
  qp4[(size_t)bc * 1024 + y4 * 32 + x4] = m4;
}

// ---------------------------------------------------------------------------
// Pooled attention IN-PLACE: qp[p] <- (act(qp*scale) @ kv) / max(..., eps).
// ---------------------------------------------------------------------------
__global__ __launch_bounds__(256) void pooled_attn(
    float* qp, const float* __restrict__ kvbuf,
    const float* __restrict__ ksumbuf, int Np)
{
  __shared__ __align__(16) float kv_s[32][32];
  __shared__ float ks_s[32];
  const int tid = threadIdx.x;
  const int bh = blockIdx.y;
  const int b = bh >> 3;
  const int head = bh & 7;
  const int p = blockIdx.x * 256 + tid;

  const float* kvb = kvbuf + (size_t)bh * 1024;
#pragma unroll
  for (int t = 0; t < 4; ++t) ((float*)kv_s)[t * 256 + tid] = kvb[t * 256 + tid];
  if (tid < 32) ks_s[tid] = ksumbuf[bh * 32 + tid];
  __syncthreads();

  float* q0 = qp + ((size_t)(b * 256 + head * 32)) * Np + p;
  float qa[32];
#pragma unroll
  for (int dd = 0; dd < 32; ++dd) qa[dd] = qk_act(q0[(size_t)dd * Np] * QK_SCALE);

  float o1[32];
#pragma unroll
  for (int e = 0; e < 32; ++e) o1[e] = 0.f;
  float norm = 0.f;
#pragma unroll
  for (int dd = 0; dd < 32; ++dd) {
    float qv = qa[dd];
    norm += qv * ks_s[dd];
#pragma unroll
    for (int e4 = 0; e4 < 8; ++e4) {
      float4 kvv = *(const float4*)&kv_s[dd][e4 * 4];
      o1[e4 * 4 + 0] += qv * kvv.x;
      o1[e4 * 4 + 1] += qv * kvv.y;
      o1[e4 * 4 + 2] += qv * kvv.z;
      o1[e4 * 4 + 3] += qv * kvv.w;
    }
  }
  norm = fmaxf(norm, 1e-6f);
  float inv1 = 1.0f / norm;
#pragma unroll
  for (int e = 0; e < 32; ++e) q0[(size_t)e * Np] = o1[e] * inv1;
}

// ---------------------------------------------------------------------------
// Fused final: scale-1 attention + bilinear upsample of pooled outputs
// (staged in LDS), softmax-weighted; emits proj input HEAD-MAJOR
// [b][head][n][32] bf16 hi/lo -> fully coalesced 64B/thread writes.
// Block: one (row-pair m, bh): 256 px, 2 image rows {2m, 2m+1}.
// ---------------------------------------------------------------------------
__global__ __launch_bounds__(256) void fused_out(
    const float* __restrict__ qkv, const float* __restrict__ kvbuf,
    const float* __restrict__ ksumbuf, const float* __restrict__ ao2,
    const float* __restrict__ ao4, const float* __restrict__ swin,
    unsigned short* __restrict__ preh, unsigned short* __restrict__ prel,
    size_t PBS)
{
  __shared__ __align__(16) float kv_s[32][32];     //  4 KB
  __shared__ float ks_s[32];
  __shared__ __align__(16) float a2_s[3][32][64];  // 24 KB: [row][e][x]
  __shared__ __align__(16) float a4_s[3][32][32];  // 12 KB
  const int tid = threadIdx.x;
  const int m  = blockIdx.x;            // row-pair index, y in {2m, 2m+1}
  const int bh = blockIdx.y;
  const int b = bh >> 3;
  const int head = bh & 7;
  const int n = m * 256 + tid;

  const float* kvb = kvbuf + (size_t)bh * 1024;
#pragma unroll
  for (int t = 0; t < 4; ++t) ((float*)kv_s)[t * 256 + tid] = kvb[t * 256 + tid];
  if (tid < 32) ks_s[tid] = ksumbuf[bh * 32 + tid];

  const float* a2 = ao2 + ((size_t)(b * 256 + head * 32)) * 4096;
  const float* a4 = ao4 + ((size_t)(b * 256 + head * 32)) * 1024;
  const int p = m >> 1;
  int r2[3], r4[3];
#pragma unroll
  for (int j = 0; j < 3; ++j) {
    int a = m - 1 + j; r2[j] = a < 0 ? 0 : (a > 63 ? 63 : a);
    int c = p - 1 + j; r4[j] = c < 0 ? 0 : (c > 31 ? 31 : c);
  }
  // stage ao2 rows {m-1,m,m+1}: 1536 float4, coalesced
#pragma unroll
  for (int t = 0; t < 6; ++t) {
    int fidx = t * 256 + tid;
    int x4 = fidx & 15, e = (fidx >> 4) & 31, j = fidx >> 9;
    *(float4*)&a2_s[j][e][x4 * 4] =
        *(const float4*)(a2 + (size_t)e * 4096 + r2[j] * 64 + x4 * 4);
  }
  // stage ao4 rows {p-1,p,p+1}: 768 float4
#pragma unroll
  for (int t = 0; t < 3; ++t) {
    int fidx = t * 256 + tid;
    int x4 = fidx & 7, e = (fidx >> 3) & 31, j = fidx >> 8;
    *(float4*)&a4_s[j][e][x4 * 4] =
        *(const float4*)(a4 + (size_t)e * 1024 + r4[j] * 32 + x4 * 4);
  }
  __syncthreads();

  float s0 = swin[0], s1 = swin[1], s2 = swin[2];
  float mx = fmaxf(s0, fmaxf(s1, s2));
  float ex0 = __expf(s0 - mx), ex1 = __expf(s1 - mx), ex2 = __expf(s2 - mx);
  float sinv = 1.0f / (ex0 + ex1 + ex2);
  float sw0 = ex0 * sinv, sw1 = ex1 * sinv, sw2 = ex2 * sinv;

  // ---- scale-1 linear attention for this pixel ----
  const float* q0 = qkv + ((size_t)b * 768 + head * 32) * GN + n;
  float qa[32];
#pragma unroll
  for (int dd = 0; dd < 32; ++dd) qa[dd] = qk_act(q0[(size_t)dd * GN] * QK_SCALE);

  float o1[32];
#pragma unroll
  for (int e = 0; e < 32; ++e) o1[e] = 0.f;
  float norm = 0.f;
#pragma unroll
  for (int dd = 0; dd < 32; ++dd) {
    float qv = qa[dd];
    norm += qv * ks_s[dd];
#pragma unroll
    for (int e4 = 0; e4 < 8; ++e4) {
      float4 kvv = *(const float4*)&kv_s[dd][e4 * 4];
      o1[e4 * 4 + 0] += qv * kvv.x;
      o1[e4 * 4 + 1] += qv * kvv.y;
      o1[e4 * 4 + 2] += qv * kvv.z;
      o1[e4 * 4 + 3] += qv * kvv.w;
    }
  }
  norm = fmaxf(norm, 1e-6f);
  float inv1 = 1.0f / norm;

  // ---- bilinear params (closed form; half-pixel mapping) ----
  const int yb = tid >> 7;                  // 0/1 -> y = 2m + yb
  const int x  = n & 127;
  const int j2 = yb;
  const float wy2 = yb ? 0.25f : 0.75f;
  const int xu = x >> 1;
  const int x20 = xu - 1 + (x & 1);
  const float wx2 = (x & 1) ? 0.25f : 0.75f;
  const int x20c = x20 < 0 ? 0 : x20;
  const int x21c = (x20 + 1) < 63 ? (x20 + 1) : 63;
  const int j4 = m & 1;
  const float wy4 = (0.625f - 0.5f * (float)(m & 1)) + 0.25f * (float)yb;
  const int xq = x >> 2, xr = x & 3;
  const int x40 = xq - 1 + (xr >> 1);
  const float wx4 = ((xr & 1) ? 0.875f : 0.625f) - ((xr >> 1) ? 0.5f : 0.0f);
  const int x40c = x40 < 0 ? 0 : x40;
  const int x41c = (x40 + 1) < 31 ? (x40 + 1) : 31;

  const float wy2i = 1.f - wy2, wx2i = 1.f - wx2;
  const float wy4i = 1.f - wy4, wx4i = 1.f - wx4;

  // ---- combine + write head-major [head][n][32] (64B contig per thread) ----
  unsigned short* ph = preh + (size_t)b * PBS + (size_t)head * (GN * 32) + (size_t)n * 32;
  unsigned short* pl = prel + (size_t)b * PBS + (size_t)head * (GN * 32) + (size_t)n * 32;

#pragma unroll
  for (int t4 = 0; t4 < 4; ++t4) {
    us8 vh, vl;
#pragma unroll
    for (int j = 0; j < 8; ++j) {
      const int e = t4 * 8 + j;
      float u2 = wy2i * (wx2i * a2_s[j2][e][x20c] + wx2 * a2_s[j2][e][x21c])
               + wy2  * (wx2i * a2_s[j2 + 1][e][x20c] + wx2 * a2_s[j2 + 1][e][x21c]);
      float u4 = wy4i * (wx4i * a4_s[j4][e][x40c] + wx4 * a4_s[j4][e][x41c])
               + wy4  * (wx4i * a4_s[j4 + 1][e][x40c] + wx4 * a4_s[j4 + 1][e][x41c]);
      float val = sw0 * o1[e] * inv1 + sw1 * u2 + sw2 * u4;
      unsigned short hh = f2bf_rn(val);
      vh[j] = hh;
      vl[j] = f2bf_rn(val - bf2f(hh));
    }
    *(us8*)(ph + t4 * 8) = vh;
    *(us8*)(pl + t4 * 8) = vl;
  }
}

// ---------------------------------------------------------------------------
extern "C" void kernel_launch(void* const* d_in, const int* in_sizes, int n_in,
                              void* d_out, int out_size, void* d_ws, size_t ws_size,
                              hipStream_t stream) {
  const float* x     = (const float*)d_in[0];
  const float* Wqkv  = (const float*)d_in[1];
  const float* Wproj = (const float*)d_in[2];
  const float* swin  = (const float*)d_in[3];
  float* out = (float*)d_out;
  float* ws  = (float*)d_ws;

  // ---- workspace layout (floats); total 59,016,192 f = 236.1 MB ----
  float* qkv = ws;                                   // 50,331,648 f
  float* xtreg = ws + (size_t)50331648;              // 8,388,608 f region
  // xt: 2-batch transposed split x; pools+partials overlay after xt is dead
  unsigned short* xt_h = (unsigned short*)xtreg;     // 2 x 4,194,304 us
  unsigned short* xt_l = xt_h + (size_t)8388608;     // 2 x 4,194,304 us
  float* qp2 = xtreg;                                // 4,194,304 f (in-place ao2)
  float* qp4 = xtreg + (size_t)4194304;              // 1,048,576 f (in-place ao4)
  float* part = xtreg + (size_t)5242880;             // 2,162,688 f (kv partials)
  float* kvb  = xtreg + (size_t)8388608;             // 32,768 f
  float* ksum = kvb + 32768;                         // 1,024 f
  unsigned short* wh1 = (unsigned short*)(ksum + 1024);  // 196,608 us
  unsigned short* wl1 = wh1 + 196608;                // 196,608 us
  unsigned short* wh2 = wl1 + 196608;                // 65,536 us
  unsigned short* wl2 = wh2 + 65536;                 // 65,536 us
  // pre (proj input) overlaid on dead v region of qkv; head-major bf16 hi/lo
  unsigned short* preh = (unsigned short*)qkv + (size_t)1024 * GN;
  unsigned short* prel = (unsigned short*)qkv + (size_t)1280 * GN;
  const size_t PBS = (size_t)1536 * GN;              // per-batch stride (ushorts)

  dim3 blk(256);
  // 0. weight splits
  split_w<<<dim3(192), blk, 0, stream>>>(Wqkv, wh1, wl1, 49152);
  split_w<<<dim3(64),  blk, 0, stream>>>(Wproj, wh2, wl2, 16384);
  // 1+2. per 2-batch group: transpose+split both slabs, then one 1536-block GEMM
  for (int g = 0; g < 2; ++g) {
    split_x_t<<<dim3(256, 8, 2), blk, 0, stream>>>(
        x + (size_t)g * 2 * 256 * GN, xt_h, xt_l);
    gemm_mfma<768, true, false><<<dim3(1536), blk, 0, stream>>>(
        wh1, wl1, xt_h, xt_l, qkv + (size_t)g * 2 * 768 * GN, (size_t)GN * 256);
  }
  // 3a. kv + ksum partials (64 chunks x 32 bh, no atomics)
  kv_ksum<<<dim3(64, 32), blk, 0, stream>>>(qkv, part);
  // 3b. reduce partials -> kvb, ksum
  kv_reduce<<<dim3(132), blk, 0, stream>>>(part, kvb, ksum);
  // 4. pool raw q (xt dead now; pools overlay it)
  pool_q<<<dim3(4096), blk, 0, stream>>>(qkv, qp2, qp4);
  // 5. pooled attention, in place
  pooled_attn<<<dim3(16, 32), blk, 0, stream>>>(qp2, kvb, ksum, 4096);
  pooled_attn<<<dim3(4, 32), blk, 0, stream>>>(qp4, kvb, ksum, 1024);
  // 6. fused scale-1 + upsample + weighted sum -> pre (head-major bf16 hi/lo)
  fused_out<<<dim3(64, 32), blk, 0, stream>>>(qkv, kvb, ksum, qp2, qp4, swin,
                                              preh, prel, PBS);
  // 7. projection via split-bf16 MFMA (4 batches, stride PBS, head-major X)
  gemm_mfma<256, false, true><<<dim3(1024), blk, 0, stream>>>(wh2, wl2, preh, prel, out, PBS);
}